// Round 14
// baseline (721.086 us; speedup 1.0000x reference)
//
#include <hip/hip_runtime.h>
#include <hip/hip_bf16.h>
#include <hip/hip_cooperative_groups.h>
#include <math.h>

namespace cg = cooperative_groups;

typedef __hip_bfloat16 bf16;
typedef unsigned short ushort;
typedef unsigned int uint;
typedef unsigned long long ull;
static __device__ __forceinline__ float b2f(bf16 x){ return __bfloat162float(x); }

static __device__ __forceinline__ float ldf(const void* p, int i, int isbf){
    return isbf ? b2f(((const bf16*)p)[i]) : ((const float*)p)[i];
}
static __device__ __forceinline__ uint fcode(float v){
    uint u = __float_as_uint(v);
    return (u & 0x80000000u) ? ~u : (u | 0x80000000u);
}
static __device__ __forceinline__ float fdecode(uint c){
    uint u = (c & 0x80000000u) ? (c & 0x7FFFFFFFu) : ~c;
    return __uint_as_float(u);
}

#define NN    4096
#define FEAT0 500
#define DIN   512
#define NH    256
#define KL1   3072
#define KL2   2304
#define KL3   1728
#define EDGE_CAP 786432u
#define GRID_B 256

typedef __attribute__((ext_vector_type(8)))  short v8s;
typedef __attribute__((ext_vector_type(16))) float v16f;

// ---------------- init + per-tensor dtype autodetect -----------------------
struct DtIn { const void* p[19]; int n[19]; };
__global__ void k_initall(DtIn a, unsigned* flags, float* degA, uint* maxU, float* sums,
        unsigned* ecnt, float* tmax, float* tmin){
    int i = blockIdx.x*256 + threadIdx.x;
    if (i < NN)  degA[i] = 1.0f;              // self-loop
    if (i < 768){ maxU[i] = 0x007FFFFFu; sums[i] = 0.f; }   // fcode(-inf)
    if (i < 4096){ tmax[i] = 0.f; tmin[i] = INFINITY; }
    if (i == 0){ ecnt[0]=0u; ecnt[1]=0u; ecnt[2]=0u; }
    if (blockIdx.x == 0 && threadIdx.x < 19){
        int t = threadIdx.x;
        const unsigned short* h = (const unsigned short*)a.p[t];
        int n = a.n[t]; if (n > 256) n = 256;
        int isbf = 1;
        for (int j = 0; j < n; j++){
            unsigned e = ((unsigned)h[j] >> 7) & 0xFFu;
            if (e >= 135u) isbf = 0;          // |v|>=64 impossible for true bf16 data
        }
        flags[t] = (unsigned)isbf;
    }
}

// ---------------- pos MLP + concat + W-convert (fused) ---------------------
__global__ __launch_bounds__(512) void k_prep(const void* __restrict__ feature,
        const void* __restrict__ img, const void* __restrict__ Wpos, const void* __restrict__ bpos,
        const void* __restrict__ W1, const void* __restrict__ W2, const void* __restrict__ W3,
        const unsigned* __restrict__ dflag, ushort* __restrict__ Xb, float* __restrict__ sq,
        ushort* __restrict__ Wb){
    int row = blockIdx.x, t = threadIdx.x;
    if (row < NN){
        int f_feat = (int)dflag[0], f_img = (int)dflag[1], f_wp = (int)dflag[2], f_bp = (int)dflag[3];
        float v;
        if (t < FEAT0) v = ldf(feature, row*FEAT0 + t, f_feat);
        else {
            int c = t - FEAT0;
            float acc = ldf(bpos, c, f_bp);
            #pragma unroll
            for (int d = 0; d < 6; d++) acc += ldf(img, row*6+d, f_img) * ldf(Wpos, d*12+c, f_wp);
            v = fmaxf(acc, 0.f);
        }
        bf16 vb = __float2bfloat16(v);
        Xb[row*DIN + t] = __bfloat16_as_ushort(vb);
        float vr = b2f(vb);
        __shared__ float red[512];
        red[t] = vr*vr;
        __syncthreads();
        for (int s = 256; s > 0; s >>= 1){ if (t < s) red[t] += red[t+s]; __syncthreads(); }
        if (t == 0) sq[row] = red[0];
    } else {
        int i0 = ((row - NN)*512 + t)*8;
        #pragma unroll
        for (int j = 0; j < 8; j++){
            int idx = i0 + j;
            float v;
            if (idx < 131072)       v = ldf(W1, idx,          (int)dflag[4]);
            else if (idx < 196608)  v = ldf(W2, idx - 131072, (int)dflag[6]);
            else                    v = ldf(W3, idx - 196608, (int)dflag[8]);
            Wb[idx] = __bfloat16_as_ushort(__float2bfloat16(v));
        }
    }
}

// 64x64 MFMA tile of A·B^T from row-major bf16, K cols (shared by both paths)
static __device__ __forceinline__ v16f mm_tile(const ushort* __restrict__ Arows,
        const ushort* __restrict__ Brows, int K, ushort* As, ushort* Bs,
        int tid, int wv, int l31, int hi){
    int row0 = tid >> 3, g0 = tid & 7;
    int row1 = row0 + 32;
    int d0 = row0*64 + ((g0^(row0&7))<<3);
    int d1 = row1*64 + ((g0^(row1&7))<<3);
    int wwr = wv >> 1, wwc = wv & 1;
    int ra0 = (wwr*32 + l31)*64, rbp = (wwc*32 + l31)*64;
    int fr7a = (wwr*32 + l31) & 7, fr7b = (wwc*32 + l31) & 7;
    float4 a0p = *(const float4*)(Arows + (size_t)row0*K + g0*8);
    float4 a1p = *(const float4*)(Arows + (size_t)row1*K + g0*8);
    float4 b0p = *(const float4*)(Brows + (size_t)row0*K + g0*8);
    float4 b1p = *(const float4*)(Brows + (size_t)row1*K + g0*8);
    v16f acc = {};
    int NC = K >> 6;
    for (int c = 0; c < NC; c++){
        __syncthreads();
        *(float4*)&As[d0] = a0p; *(float4*)&As[d1] = a1p;
        *(float4*)&Bs[d0] = b0p; *(float4*)&Bs[d1] = b1p;
        __syncthreads();
        if (c + 1 < NC){
            int k0 = (c+1)*64;
            a0p = *(const float4*)(Arows + (size_t)row0*K + k0 + g0*8);
            a1p = *(const float4*)(Arows + (size_t)row1*K + k0 + g0*8);
            b0p = *(const float4*)(Brows + (size_t)row0*K + k0 + g0*8);
            b1p = *(const float4*)(Brows + (size_t)row1*K + k0 + g0*8);
        }
        #pragma unroll
        for (int ks = 0; ks < 4; ks++){
            int gq = ks*2 + hi;
            v8s a = *(const v8s*)&As[ra0 + ((gq^fr7a)<<3)];
            v8s b = *(const v8s*)&Bs[rbp + ((gq^fr7b)<<3)];
            acc = __builtin_amdgcn_mfma_f32_32x32x16_bf16(a, b, acc, 0, 0, 0);
        }
    }
    return acc;
}

struct MegaP {
    const ushort* Xb; const float* sq; float* tmax; float* tmin;
    unsigned* ecnt; unsigned* E0; unsigned* E1;
    float* degA; float* degB;
    const ushort* Wb;
    float* XW; float* Xn; ushort* Pb;
    float* s1; float* z; int* perm; float* svals;
    uint* maxU; float* sums; float* out;
    const void *b1,*Wn1,*Wr1,*bs1,*b2,*Wn2,*Wr2,*bs2,*b3,*Wn3,*Wr3,*bs3;
    const unsigned* dflag;
};

// ---------------- whole pipeline after prep: one cooperative dispatch ------
__global__ __launch_bounds__(256, 2) void k_mega(MegaP P){
    cg::grid_group grid = cg::this_grid();
    __shared__ __align__(16) char smem[36864];
    ushort* As = (ushort*)smem;                  // 8 KB
    ushort* Bs = (ushort*)(smem + 8192);         // 8 KB
    float*  redt = (float*)(smem + 16384);       // 1 KB aux
    float*  zsh  = (float*)smem;                 // 16 KB (select)
    int*    rnk  = (int*)(smem + 16384);         // 16 KB (select)
    uint*   cntS = (uint*)(smem + 32768);        // 257
    uint*   eqS  = (uint*)(smem + 32768 + 1040); // 257
    unsigned* eL = (unsigned*)smem;              // 1 KB (gcn)
    __shared__ float tthrS, ra[4], rbv[4], wmx[4], wmn[4];
    __shared__ uint  wcntS[4];

    int tid = threadIdx.x;
    int lane = tid & 63, wv = tid >> 6;
    int l31 = lane & 31, hi = lane >> 5;
    int bid = blockIdx.x, nb = gridDim.x;
    int wwr = wv >> 1, wwc = wv & 1;

    // ---- P0: gram pass 1 (per-tile max/min d2) ----
    for (int tile = bid; tile < 2080; tile += nb){
        int rb = (int)((sqrtf(8.f*(float)tile + 1.f) - 1.f) * 0.5f);
        while ((rb+1)*(rb+2)/2 <= tile) rb++;
        while (rb*(rb+1)/2 > tile) rb--;
        int cb = tile - rb*(rb+1)/2;
        v16f acc = mm_tile(P.Xb + (size_t)rb*64*DIN, P.Xb + (size_t)cb*64*DIN, DIN,
                           As, Bs, tid, wv, l31, hi);
        int rbase = rb*64 + wwr*32 + 4*hi;
        int col   = cb*64 + wwc*32 + l31;
        float sqc = P.sq[col];
        float m = 0.f, mn = INFINITY;
        #pragma unroll
        for (int i = 0; i < 16; i++){
            int r = rbase + (i&3) + 8*(i>>2);
            float d2 = P.sq[r] + sqc - 2.f*acc[i];
            if (r != col) m = fmaxf(m, d2);
            if (r > col)  mn = fminf(mn, d2);
        }
        #pragma unroll
        for (int off = 32; off >= 1; off >>= 1){
            m  = fmaxf(m,  __shfl_down(m,  off));
            mn = fminf(mn, __shfl_down(mn, off));
        }
        __syncthreads();
        if (lane == 0){ wmx[wv] = m; wmn[wv] = mn; }
        __syncthreads();
        if (tid == 0){
            P.tmax[rb*64 + cb] = fmaxf(fmaxf(wmx[0], wmx[1]), fmaxf(wmx[2], wmx[3]));
            P.tmin[rb*64 + cb] = fminf(fminf(wmn[0], wmn[1]), fminf(wmn[2], wmn[3]));
        }
    }
    grid.sync();

    // ---- P1: threshold (redundant per block) ----
    {
        float m = 0.f;
        for (int i = tid; i < 4096; i += 256) m = fmaxf(m, P.tmax[i]);
        redt[tid] = m; __syncthreads();
        for (int s = 128; s > 0; s >>= 1){
            if (tid < s) redt[tid] = fmaxf(redt[tid], redt[tid+s]);
            __syncthreads();
        }
        if (tid == 0) tthrS = 0.5f * redt[0];
        __syncthreads();
    }
    float tthr = tthrS;

    // ---- P2: gram pass 2 (edges; tile-skip by exact bound) ----
    for (int tile = bid; tile < 2080; tile += nb){
        int rb = (int)((sqrtf(8.f*(float)tile + 1.f) - 1.f) * 0.5f);
        while ((rb+1)*(rb+2)/2 <= tile) rb++;
        while (rb*(rb+1)/2 > tile) rb--;
        int cb = tile - rb*(rb+1)/2;
        if (P.tmin[rb*64 + cb] >= tthr) continue;     // block-uniform
        v16f acc = mm_tile(P.Xb + (size_t)rb*64*DIN, P.Xb + (size_t)cb*64*DIN, DIN,
                           As, Bs, tid, wv, l31, hi);
        int rbase = rb*64 + wwr*32 + 4*hi;
        int col   = cb*64 + wwc*32 + l31;
        float sqc = P.sq[col];
        #pragma unroll
        for (int i = 0; i < 16; i++){
            int r = rbase + (i&3) + 8*(i>>2);
            float d2 = P.sq[r] + sqc - 2.f*acc[i];
            if (r > col && d2 < tthr){
                unsigned idx = atomicAdd(&P.ecnt[0], 1u);
                if (idx < EDGE_CAP){
                    P.E0[idx] = ((unsigned)r << 16) | (unsigned)col;
                    atomicAdd(&P.degA[r], 1.0f);
                }
            }
        }
    }
    grid.sync();

    // ---- P3: layers ----
    for (int l = 0; l < 3; l++){
        const ushort* Ab; int K, M, kk, Nnext, slotIn, slotOut;
        unsigned *eIn, *eOut; float *degIn, *degOut;
        const void *bb,*WnP,*WrP,*bsP; const unsigned *fb,*fWn,*fWr,*fbs;
        const ushort* Wl;
        if (l == 0){ Ab=P.Xb; K=DIN; M=NN;  kk=KL1; eIn=P.E0; slotIn=0; eOut=P.E1; slotOut=1;
            degIn=P.degA; degOut=P.degB; Nnext=KL1; Wl=P.Wb;
            bb=P.b1; WnP=P.Wn1; WrP=P.Wr1; bsP=P.bs1;
            fb=P.dflag+5; fWn=P.dflag+11; fWr=P.dflag+10; fbs=P.dflag+12; }
        else if (l == 1){ Ab=P.Pb; K=NH; M=KL1; kk=KL2; eIn=P.E1; slotIn=1; eOut=P.E0; slotOut=2;
            degIn=P.degB; degOut=P.degA; Nnext=KL2; Wl=P.Wb + 131072;
            bb=P.b2; WnP=P.Wn2; WrP=P.Wr2; bsP=P.bs2;
            fb=P.dflag+7; fWn=P.dflag+14; fWr=P.dflag+13; fbs=P.dflag+15; }
        else { Ab=P.Pb; K=NH; M=KL2; kk=KL3; eIn=P.E0; slotIn=2; eOut=nullptr; slotOut=-1;
            degIn=P.degA; degOut=P.degB; Nnext=0; Wl=P.Wb + 196608;
            bb=P.b3; WnP=P.Wn3; WrP=P.Wr3; bsP=P.bs3;
            fb=P.dflag+9; fWn=P.dflag+17; fWr=P.dflag+16; fbs=P.dflag+18; }

        // --- xw ---
        int ntiles = (M >> 6) * 4;
        for (int tile = bid; tile < ntiles; tile += nb){
            int rb = tile >> 2, cbn = tile & 3;
            int arow0 = tid >> 3, ag = tid & 7;
            int arow1 = arow0 + 32;
            int da0 = arow0*64 + ((ag^(arow0&7))<<3);
            int da1 = arow1*64 + ((ag^(arow1&7))<<3);
            const size_t baseA = (size_t)rb*64*K;
            int kr = tid >> 2, ng = tid & 3;
            float4 a0p = *(const float4*)(Ab + baseA + (size_t)arow0*K + ag*8);
            float4 a1p = *(const float4*)(Ab + baseA + (size_t)arow1*K + ag*8);
            float4 b0p = *(const float4*)(Wl + (size_t)kr*NH + cbn*64 + ng*16);
            float4 b1p = *(const float4*)(Wl + (size_t)kr*NH + cbn*64 + ng*16 + 8);
            v16f acc = {};
            int ra0 = (wwr*32 + l31)*64, rbp = (wwc*32 + l31)*64;
            int fr7a = (wwr*32 + l31) & 7, fr7b = (wwc*32 + l31) & 7;
            int kg = kr >> 3, k7 = kr & 7;
            int NC = K >> 6;
            for (int c = 0; c < NC; c++){
                __syncthreads();
                *(float4*)&As[da0] = a0p; *(float4*)&As[da1] = a1p;
                const ushort* bw0 = (const ushort*)&b0p;
                const ushort* bw1 = (const ushort*)&b1p;
                #pragma unroll
                for (int j = 0; j < 8; j++){
                    int nn = ng*16 + j;
                    Bs[nn*64 + ((kg^(nn&7))<<3) + k7] = bw0[j];
                }
                #pragma unroll
                for (int j = 0; j < 8; j++){
                    int nn = ng*16 + 8 + j;
                    Bs[nn*64 + ((kg^(nn&7))<<3) + k7] = bw1[j];
                }
                __syncthreads();
                if (c + 1 < NC){
                    int k0 = (c+1)*64;
                    a0p = *(const float4*)(Ab + baseA + (size_t)arow0*K + k0 + ag*8);
                    a1p = *(const float4*)(Ab + baseA + (size_t)arow1*K + k0 + ag*8);
                    b0p = *(const float4*)(Wl + (size_t)(k0+kr)*NH + cbn*64 + ng*16);
                    b1p = *(const float4*)(Wl + (size_t)(k0+kr)*NH + cbn*64 + ng*16 + 8);
                }
                #pragma unroll
                for (int ks = 0; ks < 4; ks++){
                    int gq = ks*2 + hi;
                    v8s a = *(const v8s*)&As[ra0 + ((gq^fr7a)<<3)];
                    v8s b = *(const v8s*)&Bs[rbp + ((gq^fr7b)<<3)];
                    acc = __builtin_amdgcn_mfma_f32_32x32x16_bf16(a, b, acc, 0, 0, 0);
                }
            }
            int n  = cbn*64 + wwc*32 + l31;
            int mb = rb*64 + wwr*32 + 4*hi;
            #pragma unroll
            for (int i = 0; i < 16; i++){
                int m = mb + (i&3) + 8*(i>>2);
                P.XW[(size_t)m*NH + n] = acc[i];
            }
        }
        grid.sync();

        // --- gcn + scorer ---
        unsigned E = __hip_atomic_load(&P.ecnt[slotIn], __ATOMIC_RELAXED,
                                       __HIP_MEMORY_SCOPE_AGENT);
        if (E > EDGE_CAP) E = EDGE_CAP;
        for (int row = bid; row < M; row += nb){
            __syncthreads();
            float disr = 1.0f / sqrtf(degIn[row]);
            float acc = disr * P.XW[row*NH + tid];
            for (unsigned base = 0; base < E; base += 256){
                unsigned nchunk = E - base; if (nchunk > 256) nchunk = 256;
                __syncthreads();
                if (tid < nchunk) eL[tid] = eIn[base + tid];
                __syncthreads();
                for (unsigned j = 0; j < nchunk; j++){
                    unsigned ed = eL[j];
                    if ((int)(ed >> 16) == row){
                        int src = ed & 0xFFFFu;
                        acc += (1.0f / sqrtf(degIn[src])) * P.XW[src*NH + tid];
                    }
                }
            }
            float xn = fmaxf(fmaf(disr, acc, ldf(bb, tid, (int)fb[0])), 0.f);
            P.Xn[row*NH + tid] = xn;
            float a  = xn * ldf(WnP, tid, (int)fWn[0]);
            float b2 = xn * ldf(WrP, tid, (int)fWr[0]);
            for (int off = 32; off >= 1; off >>= 1){ a += __shfl_down(a, off); b2 += __shfl_down(b2, off); }
            if ((tid & 63) == 0){ ra[wv] = a; rbv[wv] = b2; }
            __syncthreads();
            if (tid == 0){
                P.s1[row] = ra[0]+ra[1]+ra[2]+ra[3];
                P.z[row]  = rbv[0]+rbv[1]+rbv[2]+rbv[3] + ldf(bsP, 0, (int)fbs[0]);
            }
        }
        grid.sync();

        // --- select (block 0): scoredge + bisection top-k + efilter ---
        if (bid == 0){
            int N = M;
            for (int i = tid; i < N; i += 256){ zsh[i] = P.z[i]; rnk[i] = -1; }
            for (int i = tid; i < Nnext; i += 256) degOut[i] = 1.0f;
            __syncthreads();
            for (unsigned e = tid; e < E; e += 256){
                unsigned ed = eIn[e];
                atomicAdd(&zsh[ed >> 16], P.s1[ed & 0xFFFFu]);
            }
            __syncthreads();
            uint T = 0u;
            for (int bit = 31; bit >= 0; bit--){
                uint cand = T | (1u << bit);
                uint local = 0;
                #pragma unroll
                for (int j = 0; j < 16; j++){
                    int i = tid + j*256;
                    if (i < N && fcode(zsh[i]) >= cand) local++;
                }
                uint s = local;
                for (int off = 32; off >= 1; off >>= 1) s += __shfl_down(s, off);
                if (lane == 0) wcntS[wv] = s;
                __syncthreads();
                uint total = wcntS[0]+wcntS[1]+wcntS[2]+wcntS[3];
                if (total >= (uint)kk) T = cand;
                __syncthreads();
            }
            uint gt = 0, eq = 0;
            #pragma unroll
            for (int j = 0; j < 16; j++){
                int i = tid + j*256;
                if (i < N){ uint ky = fcode(zsh[i]); gt += (ky > T); eq += (ky == T); }
            }
            cntS[tid] = gt; eqS[tid] = eq;
            __syncthreads();
            if (tid == 0){
                uint s = 0;
                for (int i = 0; i < 256; i++){ uint c = cntS[i]; cntS[i] = s; s += c; }
                cntS[256] = s;
                uint se = 0;
                for (int i = 0; i < 256; i++){ uint c = eqS[i]; eqS[i] = se; se += c; }
            }
            __syncthreads();
            uint cntGT = cntS[256];
            uint rem = (uint)kk - cntGT;
            uint rgt = cntS[tid], req = eqS[tid];
            #pragma unroll
            for (int j = 0; j < 16; j++){
                int i = tid + j*256;
                if (i < N){
                    uint ky = fcode(zsh[i]);
                    if (ky > T){
                        uint r = rgt++;
                        P.perm[r] = i; P.svals[r] = tanhf(zsh[i]); rnk[i] = (int)r;
                    } else if (ky == T){
                        uint e = req++;
                        if (e < rem){
                            uint r = cntGT + e;
                            P.perm[r] = i; P.svals[r] = tanhf(zsh[i]); rnk[i] = (int)r;
                        }
                    }
                }
            }
            __syncthreads();
            if (slotOut >= 0){
                for (unsigned e = tid; e < E; e += 256){
                    unsigned ed = eIn[e];
                    int nd = rnk[ed >> 16], ns = rnk[ed & 0xFFFFu];
                    if (nd >= 0 && ns >= 0){
                        unsigned idx = atomicAdd(&P.ecnt[slotOut], 1u);
                        if (idx < EDGE_CAP){
                            eOut[idx] = ((unsigned)nd << 16) | (unsigned)ns;
                            atomicAdd(&degOut[nd], 1.0f);
                        }
                    }
                }
            }
        }
        grid.sync();

        // --- pool + readout ---
        {
            float m = -INFINITY, s = 0.f;
            for (int r = bid; r < kk; r += nb){
                int p = P.perm[r];
                float v = P.Xn[p*NH + tid] * P.svals[r];
                P.Pb[r*NH + tid] = __bfloat16_as_ushort(__float2bfloat16(v));
                m = fmaxf(m, v); s += v;
            }
            atomicMax(&P.maxU[l*NH + tid], fcode(m));
            atomicAdd(&P.sums[l*NH + tid], s);
        }
        grid.sync();
    }

    // ---- P4: writeout ----
    if (bid == 0){
        int t = tid;
        P.out[t] = fdecode(P.maxU[t]) + fdecode(P.maxU[NH + t]) + fdecode(P.maxU[2*NH + t]);
        P.out[NH + t] = P.sums[t]*(1.0f/KL1) + P.sums[NH + t]*(1.0f/KL2) + P.sums[2*NH + t]*(1.0f/KL3);
    }
}

// ======================= FALLBACK PATH (round-12, proven) ===================
template<int PASS>
__global__ __launch_bounds__(256) void k_gram(const ushort* __restrict__ Xb,
        const float* __restrict__ sq, float* __restrict__ tmax, float* __restrict__ tmin,
        unsigned* __restrict__ ecnt, unsigned* __restrict__ edges, float* __restrict__ deg){
    int rb = blockIdx.x, cb = blockIdx.y;
    if (cb > rb) return;
    int tid = threadIdx.x;
    float tthr = 0.f;
    if (PASS == 2){
        __shared__ float redt[256];
        float m = 0.f;
        for (int i = tid; i < 4096; i += 256) m = fmaxf(m, tmax[i]);
        redt[tid] = m; __syncthreads();
        for (int s = 128; s > 0; s >>= 1){
            if (tid < s) redt[tid] = fmaxf(redt[tid], redt[tid+s]);
            __syncthreads();
        }
        tthr = 0.5f * redt[0];
        if (tmin[rb*64 + cb] >= tthr) return;
    }
    __shared__ __align__(16) ushort As[64*64];
    __shared__ __align__(16) ushort Bs[64*64];
    int lane = tid & 63, wv = tid >> 6;
    int l31 = lane & 31, hi = lane >> 5;
    int wwr = wv >> 1, wwc = wv & 1;
    v16f acc = mm_tile(Xb + (size_t)rb*64*DIN, Xb + (size_t)cb*64*DIN, DIN,
                       As, Bs, tid, wv, l31, hi);
    int rbase = rb*64 + wwr*32 + 4*hi;
    int col   = cb*64 + wwc*32 + l31;
    float sqc = sq[col];
    if (PASS == 1){
        float m = 0.f, mn = INFINITY;
        #pragma unroll
        for (int i = 0; i < 16; i++){
            int r = rbase + (i&3) + 8*(i>>2);
            float d2 = sq[r] + sqc - 2.f*acc[i];
            if (r != col) m = fmaxf(m, d2);
            if (r > col)  mn = fminf(mn, d2);
        }
        #pragma unroll
        for (int off = 32; off >= 1; off >>= 1){
            m  = fmaxf(m,  __shfl_down(m,  off));
            mn = fminf(mn, __shfl_down(mn, off));
        }
        __shared__ float wmax[4], wmin[4];
        if (lane == 0){ wmax[wv] = m; wmin[wv] = mn; }
        __syncthreads();
        if (tid == 0){
            tmax[rb*64 + cb] = fmaxf(fmaxf(wmax[0], wmax[1]), fmaxf(wmax[2], wmax[3]));
            tmin[rb*64 + cb] = fminf(fminf(wmin[0], wmin[1]), fminf(wmin[2], wmin[3]));
        }
    } else {
        #pragma unroll
        for (int i = 0; i < 16; i++){
            int r = rbase + (i&3) + 8*(i>>2);
            float d2 = sq[r] + sqc - 2.f*acc[i];
            if (r > col && d2 < tthr){
                unsigned idx = atomicAdd(ecnt, 1u);
                if (idx < EDGE_CAP){
                    edges[idx] = ((unsigned)r << 16) | (unsigned)col;
                    atomicAdd(&deg[r], 1.0f);
                }
            }
        }
    }
}

__global__ __launch_bounds__(256) void k_xw(const ushort* __restrict__ Ab,
        const ushort* __restrict__ Wb, float* __restrict__ XW, int M, int K){
    int rb = blockIdx.x, cb = blockIdx.y;
    __shared__ __align__(16) ushort As[64*64];
    __shared__ __align__(16) ushort Bs[64*64];
    int tid = threadIdx.x, lane = tid & 63, wv = tid >> 6;
    int wwr = wv >> 1, wwc = wv & 1;
    int l31 = lane & 31, hi = lane >> 5;
    int arow0 = tid >> 3, ag = tid & 7;
    int arow1 = arow0 + 32;
    int da0 = arow0*64 + ((ag^(arow0&7))<<3);
    int da1 = arow1*64 + ((ag^(arow1&7))<<3);
    const size_t baseA = (size_t)rb*64*K;
    int kr = tid >> 2, ng = tid & 3;
    float4 a0p = *(const float4*)(Ab + baseA + (size_t)arow0*K + ag*8);
    float4 a1p = *(const float4*)(Ab + baseA + (size_t)arow1*K + ag*8);
    float4 b0p = *(const float4*)(Wb + (size_t)kr*NH + cb*64 + ng*16);
    float4 b1p = *(const float4*)(Wb + (size_t)kr*NH + cb*64 + ng*16 + 8);
    v16f acc = {};
    int ra0 = (wwr*32 + l31)*64, rbp = (wwc*32 + l31)*64;
    int fr7a = (wwr*32 + l31) & 7, fr7b = (wwc*32 + l31) & 7;
    int kg = kr >> 3, k7 = kr & 7;
    int NC = K >> 6;
    for (int c = 0; c < NC; c++){
        __syncthreads();
        *(float4*)&As[da0] = a0p; *(float4*)&As[da1] = a1p;
        const ushort* bw0 = (const ushort*)&b0p;
        const ushort* bw1 = (const ushort*)&b1p;
        #pragma unroll
        for (int j = 0; j < 8; j++){
            int nn = ng*16 + j;
            Bs[nn*64 + ((kg^(nn&7))<<3) + k7] = bw0[j];
        }
        #pragma unroll
        for (int j = 0; j < 8; j++){
            int nn = ng*16 + 8 + j;
            Bs[nn*64 + ((kg^(nn&7))<<3) + k7] = bw1[j];
        }
        __syncthreads();
        if (c + 1 < NC){
            int k0 = (c+1)*64;
            a0p = *(const float4*)(Ab + baseA + (size_t)arow0*K + k0 + ag*8);
            a1p = *(const float4*)(Ab + baseA + (size_t)arow1*K + k0 + ag*8);
            b0p = *(const float4*)(Wb + (size_t)(k0+kr)*NH + cb*64 + ng*16);
            b1p = *(const float4*)(Wb + (size_t)(k0+kr)*NH + cb*64 + ng*16 + 8);
        }
        #pragma unroll
        for (int ks = 0; ks < 4; ks++){
            int gq = ks*2 + hi;
            v8s a = *(const v8s*)&As[ra0 + ((gq^fr7a)<<3)];
            v8s b = *(const v8s*)&Bs[rbp + ((gq^fr7b)<<3)];
            acc = __builtin_amdgcn_mfma_f32_32x32x16_bf16(a, b, acc, 0, 0, 0);
        }
    }
    int n  = cb*64 + wwc*32 + l31;
    int mb = rb*64 + wwr*32 + 4*hi;
    #pragma unroll
    for (int i = 0; i < 16; i++){
        int m = mb + (i&3) + 8*(i>>2);
        XW[(size_t)m*NH + n] = acc[i];
    }
}

__global__ __launch_bounds__(256) void k_gcnscore(const float* __restrict__ XW,
        const unsigned* __restrict__ edges, const unsigned* __restrict__ ecnt, int slot,
        const float* __restrict__ deg, const void* __restrict__ b,
        const void* __restrict__ Wn, const void* __restrict__ Wr, const void* __restrict__ bs,
        const unsigned* __restrict__ fb, const unsigned* __restrict__ fWn,
        const unsigned* __restrict__ fWr, const unsigned* __restrict__ fbs,
        float* __restrict__ Xn, float* __restrict__ s1, float* __restrict__ z){
    int row = blockIdx.x, t = threadIdx.x;
    __shared__ unsigned eL[256];
    __shared__ unsigned Esh;
    if (t == 0){ unsigned E0 = ecnt[slot]; Esh = (E0 > EDGE_CAP) ? EDGE_CAP : E0; }
    __syncthreads();
    unsigned E = Esh;
    float disr = 1.0f / sqrtf(deg[row]);
    float acc = disr * XW[row*NH + t];
    for (unsigned base = 0; base < E; base += 256){
        unsigned nchunk = E - base; if (nchunk > 256) nchunk = 256;
        __syncthreads();
        if (t < nchunk) eL[t] = edges[base + t];
        __syncthreads();
        for (unsigned j = 0; j < nchunk; j++){
            unsigned ed = eL[j];
            if ((int)(ed >> 16) == row){
                int src = ed & 0xFFFFu;
                acc += (1.0f / sqrtf(deg[src])) * XW[src*NH + t];
            }
        }
    }
    float xn = fmaxf(fmaf(disr, acc, ldf(b, t, (int)fb[0])), 0.f);
    Xn[row*NH + t] = xn;
    float a  = xn * ldf(Wn, t, (int)fWn[0]);
    float bb = xn * ldf(Wr, t, (int)fWr[0]);
    for (int off = 32; off >= 1; off >>= 1){ a += __shfl_down(a, off); bb += __shfl_down(bb, off); }
    __shared__ float ra[4], rbv[4];
    int w = t >> 6;
    if ((t & 63) == 0){ ra[w] = a; rbv[w] = bb; }
    __syncthreads();
    if (t == 0){
        s1[row] = ra[0]+ra[1]+ra[2]+ra[3];
        z[row]  = rbv[0]+rbv[1]+rbv[2]+rbv[3] + ldf(bs, 0, (int)fbs[0]);
    }
}

__global__ __launch_bounds__(1024) void k_select(const float* __restrict__ z,
        const float* __restrict__ s1, int N, int k,
        const unsigned* __restrict__ eIn, unsigned* __restrict__ ecnt, int slotCur,
        unsigned* __restrict__ eOut, int slotOut,
        int* __restrict__ perm, float* __restrict__ svals,
        float* __restrict__ degN, int Nnext){
    __shared__ float zsh[4096];
    __shared__ int   rnk[4096];
    __shared__ uint  wcnt[16];
    __shared__ uint  wbase[16];
    __shared__ uint  sh[4];
    int t = threadIdx.x;
    int lane = t & 63, wv = t >> 6;
    for (int i = t; i < N; i += 1024){ zsh[i] = z[i]; rnk[i] = -1; }
    for (int i = t; i < Nnext; i += 1024) degN[i] = 1.0f;
    if (t == 0) sh[2] = 0u;
    __syncthreads();
    unsigned E = ecnt[slotCur]; if (E > EDGE_CAP) E = EDGE_CAP;
    for (unsigned e = t; e < E; e += 1024){
        unsigned ed = eIn[e];
        atomicAdd(&zsh[ed >> 16], s1[ed & 0xFFFFu]);
    }
    __syncthreads();
    bool v0 = t < N,        v1 = t+1024 < N,  v2 = t+2048 < N,  v3 = t+3072 < N;
    uint c0 = v0 ? fcode(zsh[t])      : 0u;
    uint c1 = v1 ? fcode(zsh[t+1024]) : 0u;
    uint c2 = v2 ? fcode(zsh[t+2048]) : 0u;
    uint c3 = v3 ? fcode(zsh[t+3072]) : 0u;
    uint T = 0u;
    for (int bit = 31; bit >= 0; bit--){
        uint cand = T | (1u << bit);
        uint c = (uint)__popcll(__ballot(v0 && c0 >= cand))
               + (uint)__popcll(__ballot(v1 && c1 >= cand))
               + (uint)__popcll(__ballot(v2 && c2 >= cand))
               + (uint)__popcll(__ballot(v3 && c3 >= cand));
        if (lane == 0) wcnt[wv] = c;
        __syncthreads();
        if (t == 0){ uint s = 0; for (int i = 0; i < 16; i++) s += wcnt[i]; sh[0] = s; }
        __syncthreads();
        if (sh[0] >= (uint)k) T = cand;
        __syncthreads();
    }
    ull b0 = __ballot(v0 && c0 > T), b1 = __ballot(v1 && c1 > T);
    ull b2 = __ballot(v2 && c2 > T), b3 = __ballot(v3 && c3 > T);
    uint t0 = (uint)__popcll(b0), t1 = (uint)__popcll(b1);
    uint t2 = (uint)__popcll(b2), t3 = (uint)__popcll(b3);
    if (lane == 0) wcnt[wv] = t0 + t1 + t2 + t3;
    __syncthreads();
    if (t == 0){
        uint s = 0;
        for (int i = 0; i < 16; i++){ wbase[i] = s; s += wcnt[i]; }
        sh[1] = s;
    }
    __syncthreads();
    uint cntGT = sh[1];
    uint rem = (uint)k - cntGT;
    ull ltm = ((ull)1 << lane) - 1;
    uint off = wbase[wv];
    if (v0 && c0 > T){ uint r = off + (uint)__popcll(b0 & ltm); int i = t;
        perm[r] = i; svals[r] = tanhf(zsh[i]); rnk[i] = (int)r; }
    off += t0;
    if (v1 && c1 > T){ uint r = off + (uint)__popcll(b1 & ltm); int i = t+1024;
        perm[r] = i; svals[r] = tanhf(zsh[i]); rnk[i] = (int)r; }
    off += t1;
    if (v2 && c2 > T){ uint r = off + (uint)__popcll(b2 & ltm); int i = t+2048;
        perm[r] = i; svals[r] = tanhf(zsh[i]); rnk[i] = (int)r; }
    off += t2;
    if (v3 && c3 > T){ uint r = off + (uint)__popcll(b3 & ltm); int i = t+3072;
        perm[r] = i; svals[r] = tanhf(zsh[i]); rnk[i] = (int)r; }
    #pragma unroll
    for (int j = 0; j < 4; j++){
        int i = t + j*1024;
        bool vv = (j==0) ? v0 : (j==1) ? v1 : (j==2) ? v2 : v3;
        uint cc = (j==0) ? c0 : (j==1) ? c1 : (j==2) ? c2 : c3;
        if (vv && cc == T){
            uint e = atomicAdd(&sh[2], 1u);
            if (e < rem){
                uint r = cntGT + e;
                perm[r] = i; svals[r] = tanhf(zsh[i]); rnk[i] = (int)r;
            }
        }
    }
    __syncthreads();
    if (slotOut >= 0){
        for (unsigned e = t; e < E; e += 1024){
            unsigned ed = eIn[e];
            int nd = rnk[ed >> 16], ns = rnk[ed & 0xFFFFu];
            if (nd >= 0 && ns >= 0){
                unsigned idx = atomicAdd(&ecnt[slotOut], 1u);
                if (idx < EDGE_CAP){
                    eOut[idx] = ((unsigned)nd << 16) | (unsigned)ns;
                    atomicAdd(&degN[nd], 1.0f);
                }
            }
        }
    }
}

__global__ __launch_bounds__(256) void k_poolread(const float* __restrict__ Xn,
        const int* __restrict__ perm, const float* __restrict__ svals,
        ushort* __restrict__ Pb, int k, uint* __restrict__ maxU,
        float* __restrict__ sums, int layer){
    int b = blockIdx.x, t = threadIdx.x;
    float m = -INFINITY, s = 0.f;
    for (int r = b; r < k; r += 64){
        int p = perm[r];
        float v = Xn[p*NH + t] * svals[r];
        Pb[r*NH + t] = __bfloat16_as_ushort(__float2bfloat16(v));
        m = fmaxf(m, v); s += v;
    }
    atomicMax(&maxU[layer*NH + t], fcode(m));
    atomicAdd(&sums[layer*NH + t], s);
}

__global__ void k_writeout(const uint* __restrict__ maxU, const float* __restrict__ sums,
        float* __restrict__ out, float i1, float i2, float i3){
    int t = threadIdx.x;
    if (blockIdx.x == 0)
        out[t] = fdecode(maxU[t]) + fdecode(maxU[NH + t]) + fdecode(maxU[2*NH + t]);
    else
        out[NH + t] = sums[t]*i1 + sums[NH + t]*i2 + sums[2*NH + t]*i3;
}

// =======================================================================
extern "C" void kernel_launch(void* const* d_in, const int* in_sizes, int n_in,
                              void* d_out, int out_size, void* d_ws, size_t ws_size,
                              hipStream_t stream)
{
    const void* feature = d_in[0];
    const void* img     = d_in[1];
    const void* Wpos    = d_in[2];
    const void* bpos    = d_in[3];
    const void* W1 = d_in[4];  const void* b1 = d_in[5];
    const void* W2 = d_in[6];  const void* b2 = d_in[7];
    const void* W3 = d_in[8];  const void* b3 = d_in[9];
    const void* Wr1 = d_in[10]; const void* Wn1 = d_in[11]; const void* bs1 = d_in[12];
    const void* Wr2 = d_in[13]; const void* Wn2 = d_in[14]; const void* bs2 = d_in[15];
    const void* Wr3 = d_in[16]; const void* Wn3 = d_in[17]; const void* bs3 = d_in[18];

    char* w = (char*)d_ws;
    auto alloc = [&](size_t bytes)->char*{ char* p = w; w += (bytes + 255) & ~(size_t)255; return p; };
    ushort*   Xb    = (ushort*)  alloc((size_t)NN*DIN*2);
    float*    Xn    = (float*)   alloc((size_t)NN*NH*4);
    float*    XW    = (float*)   alloc((size_t)NN*NH*4);
    ushort*   Pb    = (ushort*)  alloc((size_t)KL1*NH*2);
    ushort*   Wb    = (ushort*)  alloc((size_t)262144*2);
    unsigned* E0    = (unsigned*)alloc((size_t)EDGE_CAP*4);
    unsigned* E1    = (unsigned*)alloc((size_t)EDGE_CAP*4);
    float*    tmax  = (float*)   alloc(4096*4);
    float*    tmin  = (float*)   alloc(4096*4);
    float*    sq    = (float*)   alloc(NN*4);
    float*    degA  = (float*)   alloc(NN*4);
    float*    degB  = (float*)   alloc(NN*4);
    float*    s1    = (float*)   alloc(NN*4);
    float*    z     = (float*)   alloc(NN*4);
    int*      perm  = (int*)     alloc(NN*4);
    float*    svals = (float*)   alloc(NN*4);
    unsigned* ecnt  = (unsigned*)alloc(256);
    unsigned* dflag = (unsigned*)alloc(256);
    uint*     maxU  = (uint*)    alloc(768*4);
    float*    sums  = (float*)   alloc(768*4);
    (void)ws_size;

    DtIn da;
    for (int i = 0; i < 19; i++){ da.p[i] = d_in[i]; da.n[i] = in_sizes[i]; }
    k_initall<<<16, 256, 0, stream>>>(da, dflag, degA, maxU, sums, ecnt, tmax, tmin);
    k_prep<<<NN + 64, 512, 0, stream>>>(feature, img, Wpos, bpos, W1, W2, W3,
            dflag, Xb, sq, Wb);

    MegaP mp;
    mp.Xb = Xb; mp.sq = sq; mp.tmax = tmax; mp.tmin = tmin;
    mp.ecnt = ecnt; mp.E0 = E0; mp.E1 = E1;
    mp.degA = degA; mp.degB = degB;
    mp.Wb = Wb; mp.XW = XW; mp.Xn = Xn; mp.Pb = Pb;
    mp.s1 = s1; mp.z = z; mp.perm = perm; mp.svals = svals;
    mp.maxU = maxU; mp.sums = sums; mp.out = (float*)d_out;
    mp.b1 = b1; mp.Wn1 = Wn1; mp.Wr1 = Wr1; mp.bs1 = bs1;
    mp.b2 = b2; mp.Wn2 = Wn2; mp.Wr2 = Wr2; mp.bs2 = bs2;
    mp.b3 = b3; mp.Wn3 = Wn3; mp.Wr3 = Wr3; mp.bs3 = bs3;
    mp.dflag = dflag;
    void* args[] = { &mp };
    hipError_t err = hipLaunchCooperativeKernel((const void*)k_mega, dim3(GRID_B),
                                                dim3(256), args, 0, stream);
    if (err != hipSuccess){
        (void)hipGetLastError();   // clear sticky error; use proven multi-kernel path
        dim3 gg(64, 64);
        k_gram<1><<<gg, 256, 0, stream>>>(Xb, sq, tmax, tmin, ecnt, E0, degA);
        k_gram<2><<<gg, 256, 0, stream>>>(Xb, sq, tmax, tmin, ecnt, E0, degA);

        k_xw<<<dim3(64,4), 256, 0, stream>>>(Xb, Wb, XW, NN, DIN);
        k_gcnscore<<<NN, 256, 0, stream>>>(XW, E0, ecnt, 0, degA, b1, Wn1, Wr1, bs1,
                dflag+5, dflag+11, dflag+10, dflag+12, Xn, s1, z);
        k_select<<<1, 1024, 0, stream>>>(z, s1, NN, KL1, E0, ecnt, 0, E1, 1,
                perm, svals, degB, KL1);
        k_poolread<<<64, 256, 0, stream>>>(Xn, perm, svals, Pb, KL1, maxU, sums, 0);

        k_xw<<<dim3(48,4), 256, 0, stream>>>(Pb, Wb + 131072, XW, KL1, NH);
        k_gcnscore<<<KL1, 256, 0, stream>>>(XW, E1, ecnt, 1, degB, b2, Wn2, Wr2, bs2,
                dflag+7, dflag+14, dflag+13, dflag+15, Xn, s1, z);
        k_select<<<1, 1024, 0, stream>>>(z, s1, KL1, KL2, E1, ecnt, 1, E0, 2,
                perm, svals, degA, KL2);
        k_poolread<<<64, 256, 0, stream>>>(Xn, perm, svals, Pb, KL2, maxU, sums, 1);

        k_xw<<<dim3(36,4), 256, 0, stream>>>(Pb, Wb + 196608, XW, KL2, NH);
        k_gcnscore<<<KL2, 256, 0, stream>>>(XW, E0, ecnt, 2, degA, b3, Wn3, Wr3, bs3,
                dflag+9, dflag+17, dflag+16, dflag+18, Xn, s1, z);
        k_select<<<1, 1024, 0, stream>>>(z, s1, KL2, KL3, E0, ecnt, 2,
                (unsigned*)nullptr, -1, perm, svals, degB, 0);
        k_poolread<<<64, 256, 0, stream>>>(Xn, perm, svals, Pb, KL3, maxU, sums, 2);

        k_writeout<<<2, 256, 0, stream>>>(maxU, sums, (float*)d_out,
                1.0f/KL1, 1.0f/KL2, 1.0f/KL3);
    }
}

// Round 15
// 520.002 us; speedup vs baseline: 1.3867x; 1.3867x over previous
//
#include <hip/hip_runtime.h>
#include <hip/hip_bf16.h>
#include <math.h>

typedef __hip_bfloat16 bf16;
typedef unsigned short ushort;
typedef unsigned int uint;
typedef unsigned long long ull;
static __device__ __forceinline__ float b2f(bf16 x){ return __bfloat162float(x); }

static __device__ __forceinline__ float ldf(const void* p, int i, int isbf){
    return isbf ? b2f(((const bf16*)p)[i]) : ((const float*)p)[i];
}
static __device__ __forceinline__ uint fcode(float v){
    uint u = __float_as_uint(v);
    return (u & 0x80000000u) ? ~u : (u | 0x80000000u);
}
static __device__ __forceinline__ float fdecode(uint c){
    uint u = (c & 0x80000000u) ? (c & 0x7FFFFFFFu) : ~c;
    return __uint_as_float(u);
}

#define NN    4096
#define FEAT0 500
#define DIN   512
#define NH    256
#define KL1   3072
#define KL2   2304
#define KL3   1728
#define EDGE_CAP 786432u

typedef __attribute__((ext_vector_type(8)))  short v8s;
typedef __attribute__((ext_vector_type(16))) float v16f;

// check min(n,256) leading 16-bit halves with 256 threads; bf16 data here has
// |v|<64 (exp<135); fp32 misread has uniform-random exponent fields.
static __device__ __forceinline__ void detect_bf16(const void* p, int n, int t,
        uint* flag){
    if (t < 256 && t < n){
        uint e = ((uint)((const ushort*)p)[t] >> 7) & 0xFFu;
        if (e >= 135u) atomicAnd(flag, 0u);
    }
}

// ---------------- prep: pos MLP + concat + W-convert + ALL inits -----------
// blocks [0,NN): rows; [NN,NN+64): W1|W2|W3 -> bf16; block NN+64: inits+dflag
struct DtIn { const void* p[19]; int n[19]; };
__global__ __launch_bounds__(512) void k_prep(DtIn da,
        ushort* __restrict__ Xb, float* __restrict__ sq, ushort* __restrict__ Wb,
        unsigned* __restrict__ dflag, float* __restrict__ degA,
        uint* __restrict__ maxU, float* __restrict__ sums,
        unsigned* __restrict__ ecnt, unsigned* __restrict__ maxd2,
        float* __restrict__ tmin){
    int row = blockIdx.x, t = threadIdx.x;
    if (row < NN){
        __shared__ uint fl[4];
        if (t < 4) fl[t] = 1u;
        __syncthreads();
        detect_bf16(da.p[0], da.n[0], t, &fl[0]);   // feature
        detect_bf16(da.p[1], da.n[1], t, &fl[1]);   // img
        detect_bf16(da.p[2], da.n[2], t, &fl[2]);   // Wpos
        detect_bf16(da.p[3], da.n[3], t, &fl[3]);   // bpos
        __syncthreads();
        int f_feat = (int)fl[0], f_img = (int)fl[1], f_wp = (int)fl[2], f_bp = (int)fl[3];
        float v;
        if (t < FEAT0) v = ldf(da.p[0], row*FEAT0 + t, f_feat);
        else {
            int c = t - FEAT0;
            float acc = ldf(da.p[3], c, f_bp);
            #pragma unroll
            for (int d = 0; d < 6; d++)
                acc += ldf(da.p[1], row*6+d, f_img) * ldf(da.p[2], d*12+c, f_wp);
            v = fmaxf(acc, 0.f);
        }
        bf16 vb = __float2bfloat16(v);
        Xb[row*DIN + t] = __bfloat16_as_ushort(vb);
        float vr = b2f(vb);                 // sq of rounded vector -> d2 exact
        __shared__ float red[512];
        red[t] = vr*vr;
        __syncthreads();
        for (int s = 256; s > 0; s >>= 1){ if (t < s) red[t] += red[t+s]; __syncthreads(); }
        if (t == 0) sq[row] = red[0];
    } else if (row < NN + 64){
        __shared__ uint fl[3];
        if (t < 3) fl[t] = 1u;
        __syncthreads();
        detect_bf16(da.p[4], da.n[4], t, &fl[0]);   // W1
        detect_bf16(da.p[6], da.n[6], t, &fl[1]);   // W2
        detect_bf16(da.p[8], da.n[8], t, &fl[2]);   // W3
        __syncthreads();
        int i0 = ((row - NN)*512 + t)*8;
        #pragma unroll
        for (int j = 0; j < 8; j++){
            int idx = i0 + j;
            float v;
            if (idx < 131072)       v = ldf(da.p[4], idx,          (int)fl[0]);
            else if (idx < 196608)  v = ldf(da.p[6], idx - 131072, (int)fl[1]);
            else                    v = ldf(da.p[8], idx - 196608, (int)fl[2]);
            Wb[idx] = __bfloat16_as_ushort(__float2bfloat16(v));
        }
    } else {
        // init block
        for (int i = t; i < NN; i += 512) degA[i] = 1.0f;
        for (int i = t; i < 4096; i += 512) tmin[i] = INFINITY;
        for (int i = t; i < 768; i += 512){ maxU[i] = 0x007FFFFFu; sums[i] = 0.f; }
        if (t == 0){ ecnt[0]=0u; ecnt[1]=0u; ecnt[2]=0u; maxd2[0]=0u; }
        if (t < 19){
            const unsigned short* h = (const unsigned short*)da.p[t];
            int n = da.n[t]; if (n > 256) n = 256;
            int isbf = 1;
            for (int j = 0; j < n; j++){
                uint e = ((uint)h[j] >> 7) & 0xFFu;
                if (e >= 135u) isbf = 0;
            }
            dflag[t] = (unsigned)isbf;
        }
    }
}

// 64x64 MFMA tile of A·B^T from row-major bf16, K cols
static __device__ __forceinline__ v16f mm_tile(const ushort* __restrict__ Arows,
        const ushort* __restrict__ Brows, int K, ushort* As, ushort* Bs,
        int tid, int wv, int l31, int hi){
    int row0 = tid >> 3, g0 = tid & 7;
    int row1 = row0 + 32;
    int d0 = row0*64 + ((g0^(row0&7))<<3);
    int d1 = row1*64 + ((g0^(row1&7))<<3);
    int wwr = wv >> 1, wwc = wv & 1;
    int ra0 = (wwr*32 + l31)*64, rbp = (wwc*32 + l31)*64;
    int fr7a = (wwr*32 + l31) & 7, fr7b = (wwc*32 + l31) & 7;
    float4 a0p = *(const float4*)(Arows + (size_t)row0*K + g0*8);
    float4 a1p = *(const float4*)(Arows + (size_t)row1*K + g0*8);
    float4 b0p = *(const float4*)(Brows + (size_t)row0*K + g0*8);
    float4 b1p = *(const float4*)(Brows + (size_t)row1*K + g0*8);
    v16f acc = {};
    int NC = K >> 6;
    for (int c = 0; c < NC; c++){
        __syncthreads();
        *(float4*)&As[d0] = a0p; *(float4*)&As[d1] = a1p;
        *(float4*)&Bs[d0] = b0p; *(float4*)&Bs[d1] = b1p;
        __syncthreads();
        if (c + 1 < NC){
            int k0 = (c+1)*64;
            a0p = *(const float4*)(Arows + (size_t)row0*K + k0 + g0*8);
            a1p = *(const float4*)(Arows + (size_t)row1*K + k0 + g0*8);
            b0p = *(const float4*)(Brows + (size_t)row0*K + k0 + g0*8);
            b1p = *(const float4*)(Brows + (size_t)row1*K + k0 + g0*8);
        }
        #pragma unroll
        for (int ks = 0; ks < 4; ks++){
            int gq = ks*2 + hi;
            v8s a = *(const v8s*)&As[ra0 + ((gq^fr7a)<<3)];
            v8s b = *(const v8s*)&Bs[rbp + ((gq^fr7b)<<3)];
            acc = __builtin_amdgcn_mfma_f32_32x32x16_bf16(a, b, acc, 0, 0, 0);
        }
    }
    return acc;
}

// ---------------- Gram via MFMA, 64x64 tile ---------------------------------
// PASS 1: per-tile min d2 (plain store) + one atomicMax(maxd2)/block.
// PASS 2: tthr = 0.5*maxd2 (scalar read); skip tile if tmin>=tthr (exact).
template<int PASS>
__global__ __launch_bounds__(256) void k_gram(const ushort* __restrict__ Xb,
        const float* __restrict__ sq, unsigned* __restrict__ maxd2,
        float* __restrict__ tmin, unsigned* __restrict__ ecnt,
        unsigned* __restrict__ edges, float* __restrict__ deg){
    int rb = blockIdx.x, cb = blockIdx.y;
    if (cb > rb) return;
    int tid = threadIdx.x;
    float tthr = 0.f;
    if (PASS == 2){
        tthr = 0.5f * __uint_as_float(maxd2[0]);
        if (tmin[rb*64 + cb] >= tthr) return;   // block-uniform skip
    }
    __shared__ __align__(16) ushort As[64*64];
    __shared__ __align__(16) ushort Bs[64*64];
    int lane = tid & 63, wv = tid >> 6;
    int l31 = lane & 31, hi = lane >> 5;
    int wwr = wv >> 1, wwc = wv & 1;
    v16f acc = mm_tile(Xb + (size_t)rb*64*DIN, Xb + (size_t)cb*64*DIN, DIN,
                       As, Bs, tid, wv, l31, hi);
    int rbase = rb*64 + wwr*32 + 4*hi;
    int col   = cb*64 + wwc*32 + l31;
    float sqc = sq[col];
    if (PASS == 1){
        float m = 0.f, mn = INFINITY;
        #pragma unroll
        for (int i = 0; i < 16; i++){
            int r = rbase + (i&3) + 8*(i>>2);
            float d2 = sq[r] + sqc - 2.f*acc[i];
            if (r != col) m = fmaxf(m, d2);
            if (r > col)  mn = fminf(mn, d2);
        }
        #pragma unroll
        for (int off = 32; off >= 1; off >>= 1){
            m  = fmaxf(m,  __shfl_down(m,  off));
            mn = fminf(mn, __shfl_down(mn, off));
        }
        __shared__ float wmax[4], wmin[4];
        if (lane == 0){ wmax[wv] = m; wmin[wv] = mn; }
        __syncthreads();
        if (tid == 0){
            float mm = fmaxf(fmaxf(wmax[0], wmax[1]), fmaxf(wmax[2], wmax[3]));
            tmin[rb*64 + cb] = fminf(fminf(wmin[0], wmin[1]), fminf(wmin[2], wmin[3]));
            atomicMax(maxd2, __float_as_uint(fmaxf(mm, 0.f)));  // non-neg: uint order ok
        }
    } else {
        #pragma unroll
        for (int i = 0; i < 16; i++){
            int r = rbase + (i&3) + 8*(i>>2);
            float d2 = sq[r] + sqc - 2.f*acc[i];
            if (r > col && d2 < tthr){
                unsigned idx = atomicAdd(ecnt, 1u);
                if (idx < EDGE_CAP){
                    edges[idx] = ((unsigned)r << 16) | (unsigned)col;  // dst<<16|src
                    atomicAdd(&deg[r], 1.0f);
                }
            }
        }
    }
}

// ---------------- X @ W via MFMA (bf16), raw output -------------------------
__global__ __launch_bounds__(256) void k_xw(const ushort* __restrict__ Ab,
        const ushort* __restrict__ Wb, float* __restrict__ XW, int M, int K){
    int rb = blockIdx.x, cb = blockIdx.y;
    __shared__ __align__(16) ushort As[64*64];
    __shared__ __align__(16) ushort Bs[64*64];
    int tid = threadIdx.x, lane = tid & 63, wv = tid >> 6;
    int wwr = wv >> 1, wwc = wv & 1;
    int l31 = lane & 31, hi = lane >> 5;
    int arow0 = tid >> 3, ag = tid & 7;
    int arow1 = arow0 + 32;
    int da0 = arow0*64 + ((ag^(arow0&7))<<3);
    int da1 = arow1*64 + ((ag^(arow1&7))<<3);
    const size_t baseA = (size_t)rb*64*K;
    int kr = tid >> 2, ng = tid & 3;
    float4 a0p = *(const float4*)(Ab + baseA + (size_t)arow0*K + ag*8);
    float4 a1p = *(const float4*)(Ab + baseA + (size_t)arow1*K + ag*8);
    float4 b0p = *(const float4*)(Wb + (size_t)kr*NH + cb*64 + ng*16);
    float4 b1p = *(const float4*)(Wb + (size_t)kr*NH + cb*64 + ng*16 + 8);
    v16f acc = {};
    int ra0 = (wwr*32 + l31)*64, rbp = (wwc*32 + l31)*64;
    int fr7a = (wwr*32 + l31) & 7, fr7b = (wwc*32 + l31) & 7;
    int kg = kr >> 3, k7 = kr & 7;
    int NC = K >> 6;
    for (int c = 0; c < NC; c++){
        __syncthreads();
        *(float4*)&As[da0] = a0p; *(float4*)&As[da1] = a1p;
        const ushort* bw0 = (const ushort*)&b0p;
        const ushort* bw1 = (const ushort*)&b1p;
        #pragma unroll
        for (int j = 0; j < 8; j++){
            int nn = ng*16 + j;
            Bs[nn*64 + ((kg^(nn&7))<<3) + k7] = bw0[j];
        }
        #pragma unroll
        for (int j = 0; j < 8; j++){
            int nn = ng*16 + 8 + j;
            Bs[nn*64 + ((kg^(nn&7))<<3) + k7] = bw1[j];
        }
        __syncthreads();
        if (c + 1 < NC){
            int k0 = (c+1)*64;
            a0p = *(const float4*)(Ab + baseA + (size_t)arow0*K + k0 + ag*8);
            a1p = *(const float4*)(Ab + baseA + (size_t)arow1*K + k0 + ag*8);
            b0p = *(const float4*)(Wb + (size_t)(k0+kr)*NH + cb*64 + ng*16);
            b1p = *(const float4*)(Wb + (size_t)(k0+kr)*NH + cb*64 + ng*16 + 8);
        }
        #pragma unroll
        for (int ks = 0; ks < 4; ks++){
            int gq = ks*2 + hi;
            v8s a = *(const v8s*)&As[ra0 + ((gq^fr7a)<<3)];
            v8s b = *(const v8s*)&Bs[rbp + ((gq^fr7b)<<3)];
            acc = __builtin_amdgcn_mfma_f32_32x32x16_bf16(a, b, acc, 0, 0, 0);
        }
    }
    int n  = cb*64 + wwc*32 + l31;
    int mb = rb*64 + wwr*32 + 4*hi;
    #pragma unroll
    for (int i = 0; i < 16; i++){
        int m = mb + (i&3) + 8*(i>>2);
        XW[(size_t)m*NH + n] = acc[i];
    }
}

// ---- fused GCN finish: edge-scan aggregation + relu + scorer --------------
__global__ __launch_bounds__(256) void k_gcnscore(const float* __restrict__ XW,
        const unsigned* __restrict__ edges, const unsigned* __restrict__ ecnt, int slot,
        const float* __restrict__ deg, const void* __restrict__ b,
        const void* __restrict__ Wn, const void* __restrict__ Wr, const void* __restrict__ bs,
        const unsigned* __restrict__ fb, const unsigned* __restrict__ fWn,
        const unsigned* __restrict__ fWr, const unsigned* __restrict__ fbs,
        float* __restrict__ Xn, float* __restrict__ s1, float* __restrict__ z){
    int row = blockIdx.x, t = threadIdx.x;
    __shared__ unsigned eL[256];
    __shared__ unsigned Esh;
    if (t == 0){ unsigned E0 = ecnt[slot]; Esh = (E0 > EDGE_CAP) ? EDGE_CAP : E0; }
    __syncthreads();
    unsigned E = Esh;
    float disr = 1.0f / sqrtf(deg[row]);
    float acc = disr * XW[row*NH + t];
    for (unsigned base = 0; base < E; base += 256){
        unsigned nchunk = E - base; if (nchunk > 256) nchunk = 256;
        __syncthreads();
        if (t < nchunk) eL[t] = edges[base + t];
        __syncthreads();
        for (unsigned j = 0; j < nchunk; j++){
            unsigned ed = eL[j];
            if ((int)(ed >> 16) == row){
                int src = ed & 0xFFFFu;
                acc += (1.0f / sqrtf(deg[src])) * XW[src*NH + t];
            }
        }
    }
    float xn = fmaxf(fmaf(disr, acc, ldf(b, t, (int)fb[0])), 0.f);
    Xn[row*NH + t] = xn;
    float a  = xn * ldf(Wn, t, (int)fWn[0]);
    float bb = xn * ldf(Wr, t, (int)fWr[0]);
    for (int off = 32; off >= 1; off >>= 1){ a += __shfl_down(a, off); bb += __shfl_down(bb, off); }
    __shared__ float ra[4], rbv[4];
    int w = t >> 6;
    if ((t & 63) == 0){ ra[w] = a; rbv[w] = bb; }
    __syncthreads();
    if (t == 0){
        s1[row] = ra[0]+ra[1]+ra[2]+ra[3];
        z[row]  = rbv[0]+rbv[1]+rbv[2]+rbv[3] + ldf(bs, 0, (int)fbs[0]);
    }
}

// ---------------- fused: scoredge + bisection top-k select + efilter -------
__global__ __launch_bounds__(1024) void k_select(const float* __restrict__ z,
        const float* __restrict__ s1, int N, int k,
        const unsigned* __restrict__ eIn, unsigned* __restrict__ ecnt, int slotCur,
        unsigned* __restrict__ eOut, int slotOut,
        int* __restrict__ perm, float* __restrict__ svals,
        float* __restrict__ degN, int Nnext){
    __shared__ float zsh[4096];
    __shared__ int   rnk[4096];
    __shared__ uint  wcnt[16];
    __shared__ uint  wbase[16];
    __shared__ uint  sh[4];
    int t = threadIdx.x;
    int lane = t & 63, wv = t >> 6;
    for (int i = t; i < N; i += 1024){ zsh[i] = z[i]; rnk[i] = -1; }
    for (int i = t; i < Nnext; i += 1024) degN[i] = 1.0f;
    if (t == 0) sh[2] = 0u;
    __syncthreads();
    unsigned E = ecnt[slotCur]; if (E > EDGE_CAP) E = EDGE_CAP;
    for (unsigned e = t; e < E; e += 1024){
        unsigned ed = eIn[e];
        atomicAdd(&zsh[ed >> 16], s1[ed & 0xFFFFu]);
    }
    __syncthreads();
    bool v0 = t < N,        v1 = t+1024 < N,  v2 = t+2048 < N,  v3 = t+3072 < N;
    uint c0 = v0 ? fcode(zsh[t])      : 0u;
    uint c1 = v1 ? fcode(zsh[t+1024]) : 0u;
    uint c2 = v2 ? fcode(zsh[t+2048]) : 0u;
    uint c3 = v3 ? fcode(zsh[t+3072]) : 0u;
    uint T = 0u;
    for (int bit = 31; bit >= 0; bit--){
        uint cand = T | (1u << bit);
        uint c = (uint)__popcll(__ballot(v0 && c0 >= cand))
               + (uint)__popcll(__ballot(v1 && c1 >= cand))
               + (uint)__popcll(__ballot(v2 && c2 >= cand))
               + (uint)__popcll(__ballot(v3 && c3 >= cand));
        if (lane == 0) wcnt[wv] = c;
        __syncthreads();
        if (t == 0){ uint s = 0; for (int i = 0; i < 16; i++) s += wcnt[i]; sh[0] = s; }
        __syncthreads();
        if (sh[0] >= (uint)k) T = cand;
        __syncthreads();
    }
    ull b0 = __ballot(v0 && c0 > T), b1 = __ballot(v1 && c1 > T);
    ull b2 = __ballot(v2 && c2 > T), b3 = __ballot(v3 && c3 > T);
    uint t0 = (uint)__popcll(b0), t1 = (uint)__popcll(b1);
    uint t2 = (uint)__popcll(b2), t3 = (uint)__popcll(b3);
    if (lane == 0) wcnt[wv] = t0 + t1 + t2 + t3;
    __syncthreads();
    if (t == 0){
        uint s = 0;
        for (int i = 0; i < 16; i++){ wbase[i] = s; s += wcnt[i]; }
        sh[1] = s;
    }
    __syncthreads();
    uint cntGT = sh[1];
    uint rem = (uint)k - cntGT;
    ull ltm = ((ull)1 << lane) - 1;
    uint off = wbase[wv];
    if (v0 && c0 > T){ uint r = off + (uint)__popcll(b0 & ltm); int i = t;
        perm[r] = i; svals[r] = tanhf(zsh[i]); rnk[i] = (int)r; }
    off += t0;
    if (v1 && c1 > T){ uint r = off + (uint)__popcll(b1 & ltm); int i = t+1024;
        perm[r] = i; svals[r] = tanhf(zsh[i]); rnk[i] = (int)r; }
    off += t1;
    if (v2 && c2 > T){ uint r = off + (uint)__popcll(b2 & ltm); int i = t+2048;
        perm[r] = i; svals[r] = tanhf(zsh[i]); rnk[i] = (int)r; }
    off += t2;
    if (v3 && c3 > T){ uint r = off + (uint)__popcll(b3 & ltm); int i = t+3072;
        perm[r] = i; svals[r] = tanhf(zsh[i]); rnk[i] = (int)r; }
    #pragma unroll
    for (int j = 0; j < 4; j++){
        int i = t + j*1024;
        bool vv = (j==0) ? v0 : (j==1) ? v1 : (j==2) ? v2 : v3;
        uint cc = (j==0) ? c0 : (j==1) ? c1 : (j==2) ? c2 : c3;
        if (vv && cc == T){
            uint e = atomicAdd(&sh[2], 1u);
            if (e < rem){
                uint r = cntGT + e;
                perm[r] = i; svals[r] = tanhf(zsh[i]); rnk[i] = (int)r;
            }
        }
    }
    __syncthreads();
    if (slotOut >= 0){
        for (unsigned e = t; e < E; e += 1024){
            unsigned ed = eIn[e];
            int nd = rnk[ed >> 16], ns = rnk[ed & 0xFFFFu];
            if (nd >= 0 && ns >= 0){
                unsigned idx = atomicAdd(&ecnt[slotOut], 1u);
                if (idx < EDGE_CAP){
                    eOut[idx] = ((unsigned)nd << 16) | (unsigned)ns;
                    atomicAdd(&degN[nd], 1.0f);
                }
            }
        }
    }
}

// ---------------- pool + readout for layers 1-2 -----------------------------
__global__ __launch_bounds__(256) void k_poolread(const float* __restrict__ Xn,
        const int* __restrict__ perm, const float* __restrict__ svals,
        ushort* __restrict__ Pb, int k, uint* __restrict__ maxU,
        float* __restrict__ sums, int layer){
    int b = blockIdx.x, t = threadIdx.x;
    float m = -INFINITY, s = 0.f;
    for (int r = b; r < k; r += 64){
        int p = perm[r];
        float v = Xn[p*NH + t] * svals[r];
        Pb[r*NH + t] = __bfloat16_as_ushort(__float2bfloat16(v));
        m = fmaxf(m, v); s += v;
    }
    atomicMax(&maxU[layer*NH + t], fcode(m));
    atomicAdd(&sums[layer*NH + t], s);
}

// ---------------- layer-3 tail: select + pool/readout + final writeout -----
__global__ __launch_bounds__(1024) void k_tail(const float* __restrict__ z,
        const float* __restrict__ s1, int N, int k,
        const unsigned* __restrict__ eIn, const unsigned* __restrict__ ecnt, int slotCur,
        int* __restrict__ perm, float* __restrict__ svals,
        const float* __restrict__ Xn, const uint* __restrict__ maxU,
        const float* __restrict__ sums, float* __restrict__ out){
    __shared__ float zsh[2304];
    __shared__ uint  wcnt[16];
    __shared__ uint  wbase[16];
    __shared__ uint  sh[4];
    __shared__ float pm[1024], ps[1024];
    int t = threadIdx.x;
    int lane = t & 63, wv = t >> 6;
    for (int i = t; i < N; i += 1024) zsh[i] = z[i];
    if (t == 0) sh[2] = 0u;
    __syncthreads();
    unsigned E = ecnt[slotCur]; if (E > EDGE_CAP) E = EDGE_CAP;
    for (unsigned e = t; e < E; e += 1024){
        unsigned ed = eIn[e];
        atomicAdd(&zsh[ed >> 16], s1[ed & 0xFFFFu]);
    }
    __syncthreads();
    // bisection top-k (N<=2304 -> 3 keys/thread)
    bool v0 = t < N, v1 = t+1024 < N, v2 = t+2048 < N;
    uint c0 = v0 ? fcode(zsh[t])      : 0u;
    uint c1 = v1 ? fcode(zsh[t+1024]) : 0u;
    uint c2 = v2 ? fcode(zsh[t+2048]) : 0u;
    uint T = 0u;
    for (int bit = 31; bit >= 0; bit--){
        uint cand = T | (1u << bit);
        uint c = (uint)__popcll(__ballot(v0 && c0 >= cand))
               + (uint)__popcll(__ballot(v1 && c1 >= cand))
               + (uint)__popcll(__ballot(v2 && c2 >= cand));
        if (lane == 0) wcnt[wv] = c;
        __syncthreads();
        if (t == 0){ uint s = 0; for (int i = 0; i < 16; i++) s += wcnt[i]; sh[0] = s; }
        __syncthreads();
        if (sh[0] >= (uint)k) T = cand;
        __syncthreads();
    }
    ull b0 = __ballot(v0 && c0 > T), b1 = __ballot(v1 && c1 > T), b2 = __ballot(v2 && c2 > T);
    uint t0 = (uint)__popcll(b0), t1 = (uint)__popcll(b1), t2 = (uint)__popcll(b2);
    if (lane == 0) wcnt[wv] = t0 + t1 + t2;
    __syncthreads();
    if (t == 0){
        uint s = 0;
        for (int i = 0; i < 16; i++){ wbase[i] = s; s += wcnt[i]; }
        sh[1] = s;
    }
    __syncthreads();
    uint cntGT = sh[1];
    uint rem = (uint)k - cntGT;
    ull ltm = ((ull)1 << lane) - 1;
    uint off = wbase[wv];
    if (v0 && c0 > T){ uint r = off + (uint)__popcll(b0 & ltm); int i = t;
        perm[r] = i; svals[r] = tanhf(zsh[i]); }
    off += t0;
    if (v1 && c1 > T){ uint r = off + (uint)__popcll(b1 & ltm); int i = t+1024;
        perm[r] = i; svals[r] = tanhf(zsh[i]); }
    off += t1;
    if (v2 && c2 > T){ uint r = off + (uint)__popcll(b2 & ltm); int i = t+2048;
        perm[r] = i; svals[r] = tanhf(zsh[i]); }
    #pragma unroll
    for (int j = 0; j < 3; j++){
        int i = t + j*1024;
        bool vv = (j==0) ? v0 : (j==1) ? v1 : v2;
        uint cc = (j==0) ? c0 : (j==1) ? c1 : c2;
        if (vv && cc == T){
            uint e = atomicAdd(&sh[2], 1u);
            if (e < rem){
                uint r = cntGT + e;
                perm[r] = i; svals[r] = tanhf(zsh[i]);
            }
        }
    }
    __syncthreads();
    // pool + readout (layer 3, no Pb needed): col = t&255, 4 row stripes
    int col = t & 255, stripe = t >> 8;
    float m = -INFINITY, s = 0.f;
    for (int r = stripe; r < k; r += 4){
        float v = Xn[perm[r]*NH + col] * svals[r];
        m = fmaxf(m, v); s += v;
    }
    pm[t] = m; ps[t] = s;
    __syncthreads();
    if (t < 256){
        float m3 = fmaxf(fmaxf(pm[t], pm[t+256]), fmaxf(pm[t+512], pm[t+768]));
        float s3 = ps[t] + ps[t+256] + ps[t+512] + ps[t+768];
        out[t] = fdecode(maxU[t]) + fdecode(maxU[NH + t]) + m3;
        out[NH + t] = sums[t]*(1.0f/KL1) + sums[NH + t]*(1.0f/KL2) + s3*(1.0f/KL3);
    }
}

// =======================================================================
extern "C" void kernel_launch(void* const* d_in, const int* in_sizes, int n_in,
                              void* d_out, int out_size, void* d_ws, size_t ws_size,
                              hipStream_t stream)
{
    const void* b1 = d_in[5];
    const void* b2 = d_in[7];
    const void* b3 = d_in[9];
    const void* Wr1 = d_in[10]; const void* Wn1 = d_in[11]; const void* bs1 = d_in[12];
    const void* Wr2 = d_in[13]; const void* Wn2 = d_in[14]; const void* bs2 = d_in[15];
    const void* Wr3 = d_in[16]; const void* Wn3 = d_in[17]; const void* bs3 = d_in[18];

    char* w = (char*)d_ws;
    auto alloc = [&](size_t bytes)->char*{ char* p = w; w += (bytes + 255) & ~(size_t)255; return p; };
    ushort*   Xb    = (ushort*)  alloc((size_t)NN*DIN*2);
    float*    Xn    = (float*)   alloc((size_t)NN*NH*4);
    float*    XW    = (float*)   alloc((size_t)NN*NH*4);
    ushort*   Pb    = (ushort*)  alloc((size_t)KL1*NH*2);
    ushort*   Wb    = (ushort*)  alloc((size_t)262144*2);
    unsigned* E0    = (unsigned*)alloc((size_t)EDGE_CAP*4);
    unsigned* E1    = (unsigned*)alloc((size_t)EDGE_CAP*4);
    float*    tmin  = (float*)   alloc(4096*4);
    float*    sq    = (float*)   alloc(NN*4);
    float*    degA  = (float*)   alloc(NN*4);
    float*    degB  = (float*)   alloc(NN*4);
    float*    s1    = (float*)   alloc(NN*4);
    float*    z     = (float*)   alloc(NN*4);
    int*      perm  = (int*)     alloc(NN*4);
    float*    svals = (float*)   alloc(NN*4);
    unsigned* ecnt  = (unsigned*)alloc(256);
    unsigned* maxd2 = (unsigned*)alloc(256);
    unsigned* dflag = (unsigned*)alloc(256);
    uint*     maxU  = (uint*)    alloc(768*4);
    float*    sums  = (float*)   alloc(768*4);
    (void)ws_size;

    DtIn da;
    for (int i = 0; i < 19; i++){ da.p[i] = d_in[i]; da.n[i] = in_sizes[i]; }

    k_prep<<<NN + 65, 512, 0, stream>>>(da, Xb, sq, Wb, dflag, degA, maxU, sums,
            ecnt, maxd2, tmin);
    dim3 gg(64, 64);
    k_gram<1><<<gg, 256, 0, stream>>>(Xb, sq, maxd2, tmin, ecnt, E0, degA);
    k_gram<2><<<gg, 256, 0, stream>>>(Xb, sq, maxd2, tmin, ecnt, E0, degA);

    // ---------------- layer 1 (N=4096 -> k=3072) ----------------
    k_xw<<<dim3(64,4), 256, 0, stream>>>(Xb, Wb, XW, NN, DIN);
    k_gcnscore<<<NN, 256, 0, stream>>>(XW, E0, ecnt, 0, degA, b1, Wn1, Wr1, bs1,
            dflag+5, dflag+11, dflag+10, dflag+12, Xn, s1, z);
    k_select<<<1, 1024, 0, stream>>>(z, s1, NN, KL1, E0, ecnt, 0, E1, 1,
            perm, svals, degB, KL1);
    k_poolread<<<64, 256, 0, stream>>>(Xn, perm, svals, Pb, KL1, maxU, sums, 0);

    // ---------------- layer 2 (N=3072 -> k=2304) ----------------
    k_xw<<<dim3(48,4), 256, 0, stream>>>(Pb, Wb + 131072, XW, KL1, NH);
    k_gcnscore<<<KL1, 256, 0, stream>>>(XW, E1, ecnt, 1, degB, b2, Wn2, Wr2, bs2,
            dflag+7, dflag+14, dflag+13, dflag+15, Xn, s1, z);
    k_select<<<1, 1024, 0, stream>>>(z, s1, KL1, KL2, E1, ecnt, 1, E0, 2,
            perm, svals, degA, KL2);
    k_poolread<<<64, 256, 0, stream>>>(Xn, perm, svals, Pb, KL2, maxU, sums, 1);

    // ---------------- layer 3 (N=2304 -> k=1728) ----------------
    k_xw<<<dim3(36,4), 256, 0, stream>>>(Pb, Wb + 196608, XW, KL2, NH);
    k_gcnscore<<<KL2, 256, 0, stream>>>(XW, E0, ecnt, 2, degA, b3, Wn3, Wr3, bs3,
            dflag+9, dflag+17, dflag+16, dflag+18, Xn, s1, z);
    k_tail<<<1, 1024, 0, stream>>>(z, s1, KL2, KL3, E0, ecnt, 2,
            perm, svals, Xn, maxU, sums, (float*)d_out);
}

// Round 16
// 300.426 us; speedup vs baseline: 2.4002x; 1.7309x over previous
//
#include <hip/hip_runtime.h>
#include <hip/hip_bf16.h>
#include <math.h>

typedef __hip_bfloat16 bf16;
typedef unsigned short ushort;
typedef unsigned int uint;
typedef unsigned long long ull;
static __device__ __forceinline__ float b2f(bf16 x){ return __bfloat162float(x); }

static __device__ __forceinline__ float ldf(const void* p, int i, int isbf){
    return isbf ? b2f(((const bf16*)p)[i]) : ((const float*)p)[i];
}
static __device__ __forceinline__ uint fcode(float v){
    uint u = __float_as_uint(v);
    return (u & 0x80000000u) ? ~u : (u | 0x80000000u);
}
static __device__ __forceinline__ float fdecode(uint c){
    uint u = (c & 0x80000000u) ? (c & 0x7FFFFFFFu) : ~c;
    return __uint_as_float(u);
}

#define NN    4096
#define FEAT0 500
#define DIN   512
#define NH    256
#define KL1   3072
#define KL2   2304
#define KL3   1728
#define EDGE_CAP 786432u

typedef __attribute__((ext_vector_type(8)))  short v8s;
typedef __attribute__((ext_vector_type(16))) float v16f;

// check min(n,256) leading 16-bit halves; bf16 data here has |v|<64 (exp<135);
// fp32 misread has uniform-random exponent fields.
static __device__ __forceinline__ void detect_bf16(const void* p, int n, int t,
        uint* flag){
    if (t < 256 && t < n){
        uint e = ((uint)((const ushort*)p)[t] >> 7) & 0xFFu;
        if (e >= 135u) atomicAnd(flag, 0u);
    }
}

// ---------------- prep: pos MLP + concat + W-convert + ALL inits -----------
// blocks [0,NN): rows; [NN,NN+64): W1|W2|W3 -> bf16; block NN+64: inits+dflag
struct DtIn { const void* p[19]; int n[19]; };
__global__ __launch_bounds__(512) void k_prep(DtIn da,
        ushort* __restrict__ Xb, float* __restrict__ sq, ushort* __restrict__ Wb,
        unsigned* __restrict__ dflag, float* __restrict__ degA,
        uint* __restrict__ maxU, float* __restrict__ sums,
        unsigned* __restrict__ ecnt, unsigned* __restrict__ maxd2,
        float* __restrict__ tmin){
    int row = blockIdx.x, t = threadIdx.x;
    if (row < NN){
        __shared__ uint fl[4];
        if (t < 4) fl[t] = 1u;
        __syncthreads();
        detect_bf16(da.p[0], da.n[0], t, &fl[0]);   // feature
        detect_bf16(da.p[1], da.n[1], t, &fl[1]);   // img
        detect_bf16(da.p[2], da.n[2], t, &fl[2]);   // Wpos
        detect_bf16(da.p[3], da.n[3], t, &fl[3]);   // bpos
        __syncthreads();
        int f_feat = (int)fl[0], f_img = (int)fl[1], f_wp = (int)fl[2], f_bp = (int)fl[3];
        float v;
        if (t < FEAT0) v = ldf(da.p[0], row*FEAT0 + t, f_feat);
        else {
            int c = t - FEAT0;
            float acc = ldf(da.p[3], c, f_bp);
            #pragma unroll
            for (int d = 0; d < 6; d++)
                acc += ldf(da.p[1], row*6+d, f_img) * ldf(da.p[2], d*12+c, f_wp);
            v = fmaxf(acc, 0.f);
        }
        bf16 vb = __float2bfloat16(v);
        Xb[row*DIN + t] = __bfloat16_as_ushort(vb);
        float vr = b2f(vb);                 // sq of rounded vector -> d2 exact
        __shared__ float red[512];
        red[t] = vr*vr;
        __syncthreads();
        for (int s = 256; s > 0; s >>= 1){ if (t < s) red[t] += red[t+s]; __syncthreads(); }
        if (t == 0) sq[row] = red[0];
    } else if (row < NN + 64){
        __shared__ uint fl[3];
        if (t < 3) fl[t] = 1u;
        __syncthreads();
        detect_bf16(da.p[4], da.n[4], t, &fl[0]);   // W1
        detect_bf16(da.p[6], da.n[6], t, &fl[1]);   // W2
        detect_bf16(da.p[8], da.n[8], t, &fl[2]);   // W3
        __syncthreads();
        int i0 = ((row - NN)*512 + t)*8;
        #pragma unroll
        for (int j = 0; j < 8; j++){
            int idx = i0 + j;
            float v;
            if (idx < 131072)       v = ldf(da.p[4], idx,          (int)fl[0]);
            else if (idx < 196608)  v = ldf(da.p[6], idx - 131072, (int)fl[1]);
            else                    v = ldf(da.p[8], idx - 196608, (int)fl[2]);
            Wb[idx] = __bfloat16_as_ushort(__float2bfloat16(v));
        }
    } else {
        for (int i = t; i < NN; i += 512) degA[i] = 1.0f;
        for (int i = t; i < 4096; i += 512) tmin[i] = INFINITY;
        for (int i = t; i < 768; i += 512){ maxU[i] = 0x007FFFFFu; sums[i] = 0.f; }
        if (t == 0){ ecnt[0]=0u; ecnt[1]=0u; ecnt[2]=0u; maxd2[0]=0u; }
        if (t < 19){
            const unsigned short* h = (const unsigned short*)da.p[t];
            int n = da.n[t]; if (n > 256) n = 256;
            int isbf = 1;
            for (int j = 0; j < n; j++){
                uint e = ((uint)h[j] >> 7) & 0xFFu;
                if (e >= 135u) isbf = 0;
            }
            dflag[t] = (unsigned)isbf;
        }
    }
}

// 64x64 MFMA tile of A·B^T from row-major bf16, K cols
static __device__ __forceinline__ v16f mm_tile(const ushort* __restrict__ Arows,
        const ushort* __restrict__ Brows, int K, ushort* As, ushort* Bs,
        int tid, int wv, int l31, int hi){
    int row0 = tid >> 3, g0 = tid & 7;
    int row1 = row0 + 32;
    int d0 = row0*64 + ((g0^(row0&7))<<3);
    int d1 = row1*64 + ((g0^(row1&7))<<3);
    int wwr = wv >> 1, wwc = wv & 1;
    int ra0 = (wwr*32 + l31)*64, rbp = (wwc*32 + l31)*64;
    int fr7a = (wwr*32 + l31) & 7, fr7b = (wwc*32 + l31) & 7;
    float4 a0p = *(const float4*)(Arows + (size_t)row0*K + g0*8);
    float4 a1p = *(const float4*)(Arows + (size_t)row1*K + g0*8);
    float4 b0p = *(const float4*)(Brows + (size_t)row0*K + g0*8);
    float4 b1p = *(const float4*)(Brows + (size_t)row1*K + g0*8);
    v16f acc = {};
    int NC = K >> 6;
    for (int c = 0; c < NC; c++){
        __syncthreads();
        *(float4*)&As[d0] = a0p; *(float4*)&As[d1] = a1p;
        *(float4*)&Bs[d0] = b0p; *(float4*)&Bs[d1] = b1p;
        __syncthreads();
        if (c + 1 < NC){
            int k0 = (c+1)*64;
            a0p = *(const float4*)(Arows + (size_t)row0*K + k0 + g0*8);
            a1p = *(const float4*)(Arows + (size_t)row1*K + k0 + g0*8);
            b0p = *(const float4*)(Brows + (size_t)row0*K + k0 + g0*8);
            b1p = *(const float4*)(Brows + (size_t)row1*K + k0 + g0*8);
        }
        #pragma unroll
        for (int ks = 0; ks < 4; ks++){
            int gq = ks*2 + hi;
            v8s a = *(const v8s*)&As[ra0 + ((gq^fr7a)<<3)];
            v8s b = *(const v8s*)&Bs[rbp + ((gq^fr7b)<<3)];
            acc = __builtin_amdgcn_mfma_f32_32x32x16_bf16(a, b, acc, 0, 0, 0);
        }
    }
    return acc;
}

// ---------------- Gram via MFMA, 64x64 tile ---------------------------------
template<int PASS>
__global__ __launch_bounds__(256) void k_gram(const ushort* __restrict__ Xb,
        const float* __restrict__ sq, unsigned* __restrict__ maxd2,
        float* __restrict__ tmin, unsigned* __restrict__ ecnt,
        unsigned* __restrict__ edges, float* __restrict__ deg){
    int rb = blockIdx.x, cb = blockIdx.y;
    if (cb > rb) return;
    int tid = threadIdx.x;
    float tthr = 0.f;
    if (PASS == 2){
        tthr = 0.5f * __uint_as_float(maxd2[0]);
        if (tmin[rb*64 + cb] >= tthr) return;   // block-uniform skip (exact bound)
    }
    __shared__ __align__(16) ushort As[64*64];
    __shared__ __align__(16) ushort Bs[64*64];
    int lane = tid & 63, wv = tid >> 6;
    int l31 = lane & 31, hi = lane >> 5;
    int wwr = wv >> 1, wwc = wv & 1;
    v16f acc = mm_tile(Xb + (size_t)rb*64*DIN, Xb + (size_t)cb*64*DIN, DIN,
                       As, Bs, tid, wv, l31, hi);
    int rbase = rb*64 + wwr*32 + 4*hi;
    int col   = cb*64 + wwc*32 + l31;
    float sqc = sq[col];
    if (PASS == 1){
        float m = 0.f, mn = INFINITY;
        #pragma unroll
        for (int i = 0; i < 16; i++){
            int r = rbase + (i&3) + 8*(i>>2);
            float d2 = sq[r] + sqc - 2.f*acc[i];
            if (r != col) m = fmaxf(m, d2);
            if (r > col)  mn = fminf(mn, d2);
        }
        #pragma unroll
        for (int off = 32; off >= 1; off >>= 1){
            m  = fmaxf(m,  __shfl_down(m,  off));
            mn = fminf(mn, __shfl_down(mn, off));
        }
        __shared__ float wmax[4], wmin[4];
        if (lane == 0){ wmax[wv] = m; wmin[wv] = mn; }
        __syncthreads();
        if (tid == 0){
            float mm = fmaxf(fmaxf(wmax[0], wmax[1]), fmaxf(wmax[2], wmax[3]));
            tmin[rb*64 + cb] = fminf(fminf(wmin[0], wmin[1]), fminf(wmin[2], wmin[3]));
            atomicMax(maxd2, __float_as_uint(fmaxf(mm, 0.f)));  // non-neg: uint order ok
        }
    } else {
        #pragma unroll
        for (int i = 0; i < 16; i++){
            int r = rbase + (i&3) + 8*(i>>2);
            float d2 = sq[r] + sqc - 2.f*acc[i];
            if (r > col && d2 < tthr){
                unsigned idx = atomicAdd(ecnt, 1u);
                if (idx < EDGE_CAP){
                    edges[idx] = ((unsigned)r << 16) | (unsigned)col;  // dst<<16|src
                    atomicAdd(&deg[r], 1.0f);
                }
            }
        }
    }
}

// ---------------- X @ W via MFMA (bf16), raw output -------------------------
__global__ __launch_bounds__(256) void k_xw(const ushort* __restrict__ Ab,
        const ushort* __restrict__ Wb, float* __restrict__ XW, int M, int K){
    int rb = blockIdx.x, cb = blockIdx.y;
    __shared__ __align__(16) ushort As[64*64];
    __shared__ __align__(16) ushort Bs[64*64];
    int tid = threadIdx.x, lane = tid & 63, wv = tid >> 6;
    int wwr = wv >> 1, wwc = wv & 1;
    int l31 = lane & 31, hi = lane >> 5;
    int arow0 = tid >> 3, ag = tid & 7;
    int arow1 = arow0 + 32;
    int da0 = arow0*64 + ((ag^(arow0&7))<<3);
    int da1 = arow1*64 + ((ag^(arow1&7))<<3);
    const size_t baseA = (size_t)rb*64*K;
    int kr = tid >> 2, ng = tid & 3;
    float4 a0p = *(const float4*)(Ab + baseA + (size_t)arow0*K + ag*8);
    float4 a1p = *(const float4*)(Ab + baseA + (size_t)arow1*K + ag*8);
    float4 b0p = *(const float4*)(Wb + (size_t)kr*NH + cb*64 + ng*16);
    float4 b1p = *(const float4*)(Wb + (size_t)kr*NH + cb*64 + ng*16 + 8);
    v16f acc = {};
    int ra0 = (wwr*32 + l31)*64, rbp = (wwc*32 + l31)*64;
    int fr7a = (wwr*32 + l31) & 7, fr7b = (wwc*32 + l31) & 7;
    int kg = kr >> 3, k7 = kr & 7;
    int NC = K >> 6;
    for (int c = 0; c < NC; c++){
        __syncthreads();
        *(float4*)&As[da0] = a0p; *(float4*)&As[da1] = a1p;
        const ushort* bw0 = (const ushort*)&b0p;
        const ushort* bw1 = (const ushort*)&b1p;
        #pragma unroll
        for (int j = 0; j < 8; j++){
            int nn = ng*16 + j;
            Bs[nn*64 + ((kg^(nn&7))<<3) + k7] = bw0[j];
        }
        #pragma unroll
        for (int j = 0; j < 8; j++){
            int nn = ng*16 + 8 + j;
            Bs[nn*64 + ((kg^(nn&7))<<3) + k7] = bw1[j];
        }
        __syncthreads();
        if (c + 1 < NC){
            int k0 = (c+1)*64;
            a0p = *(const float4*)(Ab + baseA + (size_t)arow0*K + k0 + ag*8);
            a1p = *(const float4*)(Ab + baseA + (size_t)arow1*K + k0 + ag*8);
            b0p = *(const float4*)(Wb + (size_t)(k0+kr)*NH + cb*64 + ng*16);
            b1p = *(const float4*)(Wb + (size_t)(k0+kr)*NH + cb*64 + ng*16 + 8);
        }
        #pragma unroll
        for (int ks = 0; ks < 4; ks++){
            int gq = ks*2 + hi;
            v8s a = *(const v8s*)&As[ra0 + ((gq^fr7a)<<3)];
            v8s b = *(const v8s*)&Bs[rbp + ((gq^fr7b)<<3)];
            acc = __builtin_amdgcn_mfma_f32_32x32x16_bf16(a, b, acc, 0, 0, 0);
        }
    }
    int n  = cb*64 + wwc*32 + l31;
    int mb = rb*64 + wwr*32 + 4*hi;
    #pragma unroll
    for (int i = 0; i < 16; i++){
        int m = mb + (i&3) + 8*(i>>2);
        XW[(size_t)m*NH + n] = acc[i];
    }
}

// ---- fused GCN finish: edge-scan aggregation + relu + scorer --------------
__global__ __launch_bounds__(256) void k_gcnscore(const float* __restrict__ XW,
        const unsigned* __restrict__ edges, const unsigned* __restrict__ ecnt, int slot,
        const float* __restrict__ deg, const void* __restrict__ b,
        const void* __restrict__ Wn, const void* __restrict__ Wr, const void* __restrict__ bs,
        const unsigned* __restrict__ fb, const unsigned* __restrict__ fWn,
        const unsigned* __restrict__ fWr, const unsigned* __restrict__ fbs,
        float* __restrict__ Xn, float* __restrict__ s1, float* __restrict__ z){
    int row = blockIdx.x, t = threadIdx.x;
    __shared__ unsigned eL[256];
    __shared__ unsigned Esh;
    if (t == 0){ unsigned E0 = ecnt[slot]; Esh = (E0 > EDGE_CAP) ? EDGE_CAP : E0; }
    __syncthreads();
    unsigned E = Esh;
    float disr = 1.0f / sqrtf(deg[row]);
    float acc = disr * XW[row*NH + t];
    for (unsigned base = 0; base < E; base += 256){
        unsigned nchunk = E - base; if (nchunk > 256) nchunk = 256;
        __syncthreads();
        if (t < nchunk) eL[t] = edges[base + t];
        __syncthreads();
        for (unsigned j = 0; j < nchunk; j++){
            unsigned ed = eL[j];
            if ((int)(ed >> 16) == row){
                int src = ed & 0xFFFFu;
                acc += (1.0f / sqrtf(deg[src])) * XW[src*NH + t];
            }
        }
    }
    float xn = fmaxf(fmaf(disr, acc, ldf(b, t, (int)fb[0])), 0.f);
    Xn[row*NH + t] = xn;
    float a  = xn * ldf(Wn, t, (int)fWn[0]);
    float bb = xn * ldf(Wr, t, (int)fWr[0]);
    for (int off = 32; off >= 1; off >>= 1){ a += __shfl_down(a, off); bb += __shfl_down(bb, off); }
    __shared__ float ra[4], rbv[4];
    int w = t >> 6;
    if ((t & 63) == 0){ ra[w] = a; rbv[w] = bb; }
    __syncthreads();
    if (t == 0){
        s1[row] = ra[0]+ra[1]+ra[2]+ra[3];
        z[row]  = rbv[0]+rbv[1]+rbv[2]+rbv[3] + ldf(bs, 0, (int)fbs[0]);
    }
}

// ---------------- fused: scoredge + bisection top-k select + efilter -------
__global__ __launch_bounds__(1024) void k_select(const float* __restrict__ z,
        const float* __restrict__ s1, int N, int k,
        const unsigned* __restrict__ eIn, unsigned* __restrict__ ecnt, int slotCur,
        unsigned* __restrict__ eOut, int slotOut,
        int* __restrict__ perm, float* __restrict__ svals,
        float* __restrict__ degN, int Nnext){
    __shared__ float zsh[4096];
    __shared__ int   rnk[4096];
    __shared__ uint  wcnt[16];
    __shared__ uint  wbase[16];
    __shared__ uint  sh[4];
    int t = threadIdx.x;
    int lane = t & 63, wv = t >> 6;
    for (int i = t; i < N; i += 1024){ zsh[i] = z[i]; rnk[i] = -1; }
    for (int i = t; i < Nnext; i += 1024) degN[i] = 1.0f;
    if (t == 0) sh[2] = 0u;
    __syncthreads();
    unsigned E = ecnt[slotCur]; if (E > EDGE_CAP) E = EDGE_CAP;
    for (unsigned e = t; e < E; e += 1024){
        unsigned ed = eIn[e];
        atomicAdd(&zsh[ed >> 16], s1[ed & 0xFFFFu]);
    }
    __syncthreads();
    bool v0 = t < N,        v1 = t+1024 < N,  v2 = t+2048 < N,  v3 = t+3072 < N;
    uint c0 = v0 ? fcode(zsh[t])      : 0u;
    uint c1 = v1 ? fcode(zsh[t+1024]) : 0u;
    uint c2 = v2 ? fcode(zsh[t+2048]) : 0u;
    uint c3 = v3 ? fcode(zsh[t+3072]) : 0u;
    uint T = 0u;
    for (int bit = 31; bit >= 0; bit--){
        uint cand = T | (1u << bit);
        uint c = (uint)__popcll(__ballot(v0 && c0 >= cand))
               + (uint)__popcll(__ballot(v1 && c1 >= cand))
               + (uint)__popcll(__ballot(v2 && c2 >= cand))
               + (uint)__popcll(__ballot(v3 && c3 >= cand));
        if (lane == 0) wcnt[wv] = c;
        __syncthreads();
        if (t == 0){ uint s = 0; for (int i = 0; i < 16; i++) s += wcnt[i]; sh[0] = s; }
        __syncthreads();
        if (sh[0] >= (uint)k) T = cand;
        __syncthreads();
    }
    ull b0 = __ballot(v0 && c0 > T), b1 = __ballot(v1 && c1 > T);
    ull b2 = __ballot(v2 && c2 > T), b3 = __ballot(v3 && c3 > T);
    uint t0 = (uint)__popcll(b0), t1 = (uint)__popcll(b1);
    uint t2 = (uint)__popcll(b2), t3 = (uint)__popcll(b3);
    if (lane == 0) wcnt[wv] = t0 + t1 + t2 + t3;
    __syncthreads();
    if (t == 0){
        uint s = 0;
        for (int i = 0; i < 16; i++){ wbase[i] = s; s += wcnt[i]; }
        sh[1] = s;
    }
    __syncthreads();
    uint cntGT = sh[1];
    uint rem = (uint)k - cntGT;
    ull ltm = ((ull)1 << lane) - 1;
    uint off = wbase[wv];
    if (v0 && c0 > T){ uint r = off + (uint)__popcll(b0 & ltm); int i = t;
        perm[r] = i; svals[r] = tanhf(zsh[i]); rnk[i] = (int)r; }
    off += t0;
    if (v1 && c1 > T){ uint r = off + (uint)__popcll(b1 & ltm); int i = t+1024;
        perm[r] = i; svals[r] = tanhf(zsh[i]); rnk[i] = (int)r; }
    off += t1;
    if (v2 && c2 > T){ uint r = off + (uint)__popcll(b2 & ltm); int i = t+2048;
        perm[r] = i; svals[r] = tanhf(zsh[i]); rnk[i] = (int)r; }
    off += t2;
    if (v3 && c3 > T){ uint r = off + (uint)__popcll(b3 & ltm); int i = t+3072;
        perm[r] = i; svals[r] = tanhf(zsh[i]); rnk[i] = (int)r; }
    #pragma unroll
    for (int j = 0; j < 4; j++){
        int i = t + j*1024;
        bool vv = (j==0) ? v0 : (j==1) ? v1 : (j==2) ? v2 : v3;
        uint cc = (j==0) ? c0 : (j==1) ? c1 : (j==2) ? c2 : c3;
        if (vv && cc == T){
            uint e = atomicAdd(&sh[2], 1u);
            if (e < rem){
                uint r = cntGT + e;
                perm[r] = i; svals[r] = tanhf(zsh[i]); rnk[i] = (int)r;
            }
        }
    }
    __syncthreads();
    if (slotOut >= 0){
        for (unsigned e = t; e < E; e += 1024){
            unsigned ed = eIn[e];
            int nd = rnk[ed >> 16], ns = rnk[ed & 0xFFFFu];
            if (nd >= 0 && ns >= 0){
                unsigned idx = atomicAdd(&ecnt[slotOut], 1u);
                if (idx < EDGE_CAP){
                    eOut[idx] = ((unsigned)nd << 16) | (unsigned)ns;
                    atomicAdd(&degN[nd], 1.0f);
                }
            }
        }
    }
}

// ---------------- pool + readout (64 blocks; parallel gather) ---------------
__global__ __launch_bounds__(256) void k_poolread(const float* __restrict__ Xn,
        const int* __restrict__ perm, const float* __restrict__ svals,
        ushort* __restrict__ Pb, int k, uint* __restrict__ maxU,
        float* __restrict__ sums, int layer){
    int b = blockIdx.x, t = threadIdx.x;
    float m = -INFINITY, s = 0.f;
    for (int r = b; r < k; r += 64){
        int p = perm[r];
        float v = Xn[p*NH + t] * svals[r];
        Pb[r*NH + t] = __bfloat16_as_ushort(__float2bfloat16(v));
        m = fmaxf(m, v); s += v;
    }
    atomicMax(&maxU[layer*NH + t], fcode(m));
    atomicAdd(&sums[layer*NH + t], s);
}

__global__ void k_writeout(const uint* __restrict__ maxU, const float* __restrict__ sums,
        float* __restrict__ out, float i1, float i2, float i3){
    int t = threadIdx.x;
    if (blockIdx.x == 0)
        out[t] = fdecode(maxU[t]) + fdecode(maxU[NH + t]) + fdecode(maxU[2*NH + t]);
    else
        out[NH + t] = sums[t]*i1 + sums[NH + t]*i2 + sums[2*NH + t]*i3;
}

// =======================================================================
extern "C" void kernel_launch(void* const* d_in, const int* in_sizes, int n_in,
                              void* d_out, int out_size, void* d_ws, size_t ws_size,
                              hipStream_t stream)
{
    const void* b1 = d_in[5];
    const void* b2 = d_in[7];
    const void* b3 = d_in[9];
    const void* Wr1 = d_in[10]; const void* Wn1 = d_in[11]; const void* bs1 = d_in[12];
    const void* Wr2 = d_in[13]; const void* Wn2 = d_in[14]; const void* bs2 = d_in[15];
    const void* Wr3 = d_in[16]; const void* Wn3 = d_in[17]; const void* bs3 = d_in[18];

    char* w = (char*)d_ws;
    auto alloc = [&](size_t bytes)->char*{ char* p = w; w += (bytes + 255) & ~(size_t)255; return p; };
    ushort*   Xb    = (ushort*)  alloc((size_t)NN*DIN*2);
    float*    Xn    = (float*)   alloc((size_t)NN*NH*4);
    float*    XW    = (float*)   alloc((size_t)NN*NH*4);
    ushort*   Pb    = (ushort*)  alloc((size_t)KL1*NH*2);
    ushort*   Wb    = (ushort*)  alloc((size_t)262144*2);
    unsigned* E0    = (unsigned*)alloc((size_t)EDGE_CAP*4);
    unsigned* E1    = (unsigned*)alloc((size_t)EDGE_CAP*4);
    float*    tmin  = (float*)   alloc(4096*4);
    float*    sq    = (float*)   alloc(NN*4);
    float*    degA  = (float*)   alloc(NN*4);
    float*    degB  = (float*)   alloc(NN*4);
    float*    s1    = (float*)   alloc(NN*4);
    float*    z     = (float*)   alloc(NN*4);
    int*      perm  = (int*)     alloc(NN*4);
    float*    svals = (float*)   alloc(NN*4);
    unsigned* ecnt  = (unsigned*)alloc(256);
    unsigned* maxd2 = (unsigned*)alloc(256);
    unsigned* dflag = (unsigned*)alloc(256);
    uint*     maxU  = (uint*)    alloc(768*4);
    float*    sums  = (float*)   alloc(768*4);
    (void)ws_size;

    DtIn da;
    for (int i = 0; i < 19; i++){ da.p[i] = d_in[i]; da.n[i] = in_sizes[i]; }

    k_prep<<<NN + 65, 512, 0, stream>>>(da, Xb, sq, Wb, dflag, degA, maxU, sums,
            ecnt, maxd2, tmin);
    dim3 gg(64, 64);
    k_gram<1><<<gg, 256, 0, stream>>>(Xb, sq, maxd2, tmin, ecnt, E0, degA);
    k_gram<2><<<gg, 256, 0, stream>>>(Xb, sq, maxd2, tmin, ecnt, E0, degA);

    // ---------------- layer 1 (N=4096 -> k=3072) ----------------
    k_xw<<<dim3(64,4), 256, 0, stream>>>(Xb, Wb, XW, NN, DIN);
    k_gcnscore<<<NN, 256, 0, stream>>>(XW, E0, ecnt, 0, degA, b1, Wn1, Wr1, bs1,
            dflag+5, dflag+11, dflag+10, dflag+12, Xn, s1, z);
    k_select<<<1, 1024, 0, stream>>>(z, s1, NN, KL1, E0, ecnt, 0, E1, 1,
            perm, svals, degB, KL1);
    k_poolread<<<64, 256, 0, stream>>>(Xn, perm, svals, Pb, KL1, maxU, sums, 0);

    // ---------------- layer 2 (N=3072 -> k=2304) ----------------
    k_xw<<<dim3(48,4), 256, 0, stream>>>(Pb, Wb + 131072, XW, KL1, NH);
    k_gcnscore<<<KL1, 256, 0, stream>>>(XW, E1, ecnt, 1, degB, b2, Wn2, Wr2, bs2,
            dflag+7, dflag+14, dflag+13, dflag+15, Xn, s1, z);
    k_select<<<1, 1024, 0, stream>>>(z, s1, KL1, KL2, E1, ecnt, 1, E0, 2,
            perm, svals, degA, KL2);
    k_poolread<<<64, 256, 0, stream>>>(Xn, perm, svals, Pb, KL2, maxU, sums, 1);

    // ---------------- layer 3 (N=2304 -> k=1728) ----------------
    k_xw<<<dim3(36,4), 256, 0, stream>>>(Pb, Wb + 196608, XW, KL2, NH);
    k_gcnscore<<<KL2, 256, 0, stream>>>(XW, E0, ecnt, 2, degA, b3, Wn3, Wr3, bs3,
            dflag+9, dflag+17, dflag+16, dflag+18, Xn, s1, z);
    k_select<<<1, 1024, 0, stream>>>(z, s1, KL2, KL3, E0, ecnt, 2,
            (unsigned*)nullptr, -1, perm, svals, degB, 0);
    k_poolread<<<64, 256, 0, stream>>>(Xn, perm, svals, Pb, KL3, maxU, sums, 2);

    k_writeout<<<2, 256, 0, stream>>>(maxU, sums, (float*)d_out,
            1.0f/KL1, 1.0f/KL2, 1.0f/KL3);
}

// Round 17
// 262.589 us; speedup vs baseline: 2.7461x; 1.1441x over previous
//
#include <hip/hip_runtime.h>
#include <hip/hip_bf16.h>
#include <math.h>

typedef __hip_bfloat16 bf16;
typedef unsigned short ushort;
typedef unsigned int uint;
typedef unsigned long long ull;
static __device__ __forceinline__ float b2f(bf16 x){ return __bfloat162float(x); }

static __device__ __forceinline__ float ldf(const void* p, int i, int isbf){
    return isbf ? b2f(((const bf16*)p)[i]) : ((const float*)p)[i];
}
static __device__ __forceinline__ ushort f2b(float x){
    return __bfloat16_as_ushort(__float2bfloat16(x));
}
static __device__ __forceinline__ uint fcode(float v){
    uint u = __float_as_uint(v);
    return (u & 0x80000000u) ? ~u : (u | 0x80000000u);
}
static __device__ __forceinline__ float fdecode(uint c){
    uint u = (c & 0x80000000u) ? (c & 0x7FFFFFFFu) : ~c;
    return __uint_as_float(u);
}

#define NN    4096
#define FEAT0 500
#define DIN   512
#define NH    256
#define KL1   3072
#define KL2   2304
#define KL3   1728
#define EDGE_CAP 786432u

typedef __attribute__((ext_vector_type(8)))  short v8s;
typedef __attribute__((ext_vector_type(16))) float v16f;

// check min(n,256) leading 16-bit halves; bf16 data here has |v|<64 (exp<135);
// fp32 misread has uniform-random exponent fields.
static __device__ __forceinline__ void detect_bf16(const void* p, int n, int t,
        uint* flag){
    if (t < 256 && t < n){
        uint e = ((uint)((const ushort*)p)[t] >> 7) & 0xFFu;
        if (e >= 135u) atomicAnd(flag, 0u);
    }
}

// ---------------- prep: pos MLP + concat + W-convert + ALL inits -----------
// blocks [0,NN): rows; [NN,NN+64): W1|W2|W3 -> bf16; block NN+64: inits+dflag
struct DtIn { const void* p[19]; int n[19]; };
__global__ __launch_bounds__(512) void k_prep(DtIn da,
        ushort* __restrict__ Xb, float* __restrict__ sq, ushort* __restrict__ Wb,
        unsigned* __restrict__ dflag, float* __restrict__ degA,
        uint* __restrict__ maxU, float* __restrict__ sums,
        unsigned* __restrict__ ecnt, unsigned* __restrict__ maxd2,
        float* __restrict__ tmin){
    int row = blockIdx.x, t = threadIdx.x;
    if (row < NN){
        __shared__ uint fl[4];
        if (t < 4) fl[t] = 1u;
        __syncthreads();
        detect_bf16(da.p[0], da.n[0], t, &fl[0]);   // feature
        detect_bf16(da.p[1], da.n[1], t, &fl[1]);   // img
        detect_bf16(da.p[2], da.n[2], t, &fl[2]);   // Wpos
        detect_bf16(da.p[3], da.n[3], t, &fl[3]);   // bpos
        __syncthreads();
        int f_feat = (int)fl[0], f_img = (int)fl[1], f_wp = (int)fl[2], f_bp = (int)fl[3];
        float v;
        if (t < FEAT0) v = ldf(da.p[0], row*FEAT0 + t, f_feat);
        else {
            int c = t - FEAT0;
            float acc = ldf(da.p[3], c, f_bp);
            #pragma unroll
            for (int d = 0; d < 6; d++)
                acc += ldf(da.p[1], row*6+d, f_img) * ldf(da.p[2], d*12+c, f_wp);
            v = fmaxf(acc, 0.f);
        }
        bf16 vb = __float2bfloat16(v);
        Xb[row*DIN + t] = __bfloat16_as_ushort(vb);
        float vr = b2f(vb);                 // sq of rounded vector -> d2 exact
        __shared__ float red[512];
        red[t] = vr*vr;
        __syncthreads();
        for (int s = 256; s > 0; s >>= 1){ if (t < s) red[t] += red[t+s]; __syncthreads(); }
        if (t == 0) sq[row] = red[0];
    } else if (row < NN + 64){
        __shared__ uint fl[3];
        if (t < 3) fl[t] = 1u;
        __syncthreads();
        detect_bf16(da.p[4], da.n[4], t, &fl[0]);   // W1
        detect_bf16(da.p[6], da.n[6], t, &fl[1]);   // W2
        detect_bf16(da.p[8], da.n[8], t, &fl[2]);   // W3
        __syncthreads();
        int i0 = ((row - NN)*512 + t)*8;
        #pragma unroll
        for (int j = 0; j < 8; j++){
            int idx = i0 + j;
            float v;
            if (idx < 131072)       v = ldf(da.p[4], idx,          (int)fl[0]);
            else if (idx < 196608)  v = ldf(da.p[6], idx - 131072, (int)fl[1]);
            else                    v = ldf(da.p[8], idx - 196608, (int)fl[2]);
            Wb[idx] = __bfloat16_as_ushort(__float2bfloat16(v));
        }
    } else {
        for (int i = t; i < NN; i += 512) degA[i] = 1.0f;
        for (int i = t; i < 4096; i += 512) tmin[i] = INFINITY;
        for (int i = t; i < 768; i += 512){ maxU[i] = 0x007FFFFFu; sums[i] = 0.f; }
        if (t == 0){ ecnt[0]=0u; ecnt[1]=0u; ecnt[2]=0u; ecnt[3]=0u; maxd2[0]=0u; }
        if (t < 19){
            const unsigned short* h = (const unsigned short*)da.p[t];
            int n = da.n[t]; if (n > 256) n = 256;
            int isbf = 1;
            for (int j = 0; j < n; j++){
                uint e = ((uint)h[j] >> 7) & 0xFFu;
                if (e >= 135u) isbf = 0;
            }
            dflag[t] = (unsigned)isbf;
        }
    }
}

// 64x64 MFMA tile of A·B^T from row-major bf16, K cols
static __device__ __forceinline__ v16f mm_tile(const ushort* __restrict__ Arows,
        const ushort* __restrict__ Brows, int K, ushort* As, ushort* Bs,
        int tid, int wv, int l31, int hi){
    int row0 = tid >> 3, g0 = tid & 7;
    int row1 = row0 + 32;
    int d0 = row0*64 + ((g0^(row0&7))<<3);
    int d1 = row1*64 + ((g0^(row1&7))<<3);
    int wwr = wv >> 1, wwc = wv & 1;
    int ra0 = (wwr*32 + l31)*64, rbp = (wwc*32 + l31)*64;
    int fr7a = (wwr*32 + l31) & 7, fr7b = (wwc*32 + l31) & 7;
    float4 a0p = *(const float4*)(Arows + (size_t)row0*K + g0*8);
    float4 a1p = *(const float4*)(Arows + (size_t)row1*K + g0*8);
    float4 b0p = *(const float4*)(Brows + (size_t)row0*K + g0*8);
    float4 b1p = *(const float4*)(Brows + (size_t)row1*K + g0*8);
    v16f acc = {};
    int NC = K >> 6;
    for (int c = 0; c < NC; c++){
        __syncthreads();
        *(float4*)&As[d0] = a0p; *(float4*)&As[d1] = a1p;
        *(float4*)&Bs[d0] = b0p; *(float4*)&Bs[d1] = b1p;
        __syncthreads();
        if (c + 1 < NC){
            int k0 = (c+1)*64;
            a0p = *(const float4*)(Arows + (size_t)row0*K + k0 + g0*8);
            a1p = *(const float4*)(Arows + (size_t)row1*K + k0 + g0*8);
            b0p = *(const float4*)(Brows + (size_t)row0*K + k0 + g0*8);
            b1p = *(const float4*)(Brows + (size_t)row1*K + k0 + g0*8);
        }
        #pragma unroll
        for (int ks = 0; ks < 4; ks++){
            int gq = ks*2 + hi;
            v8s a = *(const v8s*)&As[ra0 + ((gq^fr7a)<<3)];
            v8s b = *(const v8s*)&Bs[rbp + ((gq^fr7b)<<3)];
            acc = __builtin_amdgcn_mfma_f32_32x32x16_bf16(a, b, acc, 0, 0, 0);
        }
    }
    return acc;
}

// ---------------- Gram via MFMA, 64x64 tile ---------------------------------
template<int PASS>
__global__ __launch_bounds__(256) void k_gram(const ushort* __restrict__ Xb,
        const float* __restrict__ sq, unsigned* __restrict__ maxd2,
        float* __restrict__ tmin, unsigned* __restrict__ ecnt,
        unsigned* __restrict__ edges, float* __restrict__ deg){
    int rb = blockIdx.x, cb = blockIdx.y;
    if (cb > rb) return;
    int tid = threadIdx.x;
    float tthr = 0.f;
    if (PASS == 2){
        tthr = 0.5f * __uint_as_float(maxd2[0]);
        if (tmin[rb*64 + cb] >= tthr) return;   // block-uniform skip (exact bound)
    }
    __shared__ __align__(16) ushort As[64*64];
    __shared__ __align__(16) ushort Bs[64*64];
    int lane = tid & 63, wv = tid >> 6;
    int l31 = lane & 31, hi = lane >> 5;
    int wwr = wv >> 1, wwc = wv & 1;
    v16f acc = mm_tile(Xb + (size_t)rb*64*DIN, Xb + (size_t)cb*64*DIN, DIN,
                       As, Bs, tid, wv, l31, hi);
    int rbase = rb*64 + wwr*32 + 4*hi;
    int col   = cb*64 + wwc*32 + l31;
    float sqc = sq[col];
    if (PASS == 1){
        float m = 0.f, mn = INFINITY;
        #pragma unroll
        for (int i = 0; i < 16; i++){
            int r = rbase + (i&3) + 8*(i>>2);
            float d2 = sq[r] + sqc - 2.f*acc[i];
            if (r != col) m = fmaxf(m, d2);
            if (r > col)  mn = fminf(mn, d2);
        }
        #pragma unroll
        for (int off = 32; off >= 1; off >>= 1){
            m  = fmaxf(m,  __shfl_down(m,  off));
            mn = fminf(mn, __shfl_down(mn, off));
        }
        __shared__ float wmax[4], wmin[4];
        if (lane == 0){ wmax[wv] = m; wmin[wv] = mn; }
        __syncthreads();
        if (tid == 0){
            float mm = fmaxf(fmaxf(wmax[0], wmax[1]), fmaxf(wmax[2], wmax[3]));
            tmin[rb*64 + cb] = fminf(fminf(wmin[0], wmin[1]), fminf(wmin[2], wmin[3]));
            atomicMax(maxd2, __float_as_uint(fmaxf(mm, 0.f)));  // non-neg: uint order ok
        }
    } else {
        #pragma unroll
        for (int i = 0; i < 16; i++){
            int r = rbase + (i&3) + 8*(i>>2);
            float d2 = sq[r] + sqc - 2.f*acc[i];
            if (r > col && d2 < tthr){
                unsigned idx = atomicAdd(ecnt, 1u);
                if (idx < EDGE_CAP){
                    edges[idx] = ((unsigned)r << 16) | (unsigned)col;  // dst<<16|src
                    atomicAdd(&deg[r], 1.0f);
                }
            }
        }
    }
}

// ---------------- X @ W via MFMA (bf16 input), layer 1 ----------------------
__global__ __launch_bounds__(256) void k_xw(const ushort* __restrict__ Ab,
        const ushort* __restrict__ Wb, float* __restrict__ XW, int M, int K){
    int rb = blockIdx.x, cb = blockIdx.y;
    __shared__ __align__(16) ushort As[64*64];
    __shared__ __align__(16) ushort Bs[64*64];
    int tid = threadIdx.x, lane = tid & 63, wv = tid >> 6;
    int wwr = wv >> 1, wwc = wv & 1;
    int l31 = lane & 31, hi = lane >> 5;
    int arow0 = tid >> 3, ag = tid & 7;
    int arow1 = arow0 + 32;
    int da0 = arow0*64 + ((ag^(arow0&7))<<3);
    int da1 = arow1*64 + ((ag^(arow1&7))<<3);
    const size_t baseA = (size_t)rb*64*K;
    int kr = tid >> 2, ng = tid & 3;
    float4 a0p = *(const float4*)(Ab + baseA + (size_t)arow0*K + ag*8);
    float4 a1p = *(const float4*)(Ab + baseA + (size_t)arow1*K + ag*8);
    float4 b0p = *(const float4*)(Wb + (size_t)kr*NH + cb*64 + ng*16);
    float4 b1p = *(const float4*)(Wb + (size_t)kr*NH + cb*64 + ng*16 + 8);
    v16f acc = {};
    int ra0 = (wwr*32 + l31)*64, rbp = (wwc*32 + l31)*64;
    int fr7a = (wwr*32 + l31) & 7, fr7b = (wwc*32 + l31) & 7;
    int kg = kr >> 3, k7 = kr & 7;
    int NC = K >> 6;
    for (int c = 0; c < NC; c++){
        __syncthreads();
        *(float4*)&As[da0] = a0p; *(float4*)&As[da1] = a1p;
        const ushort* bw0 = (const ushort*)&b0p;
        const ushort* bw1 = (const ushort*)&b1p;
        #pragma unroll
        for (int j = 0; j < 8; j++){
            int nn = ng*16 + j;
            Bs[nn*64 + ((kg^(nn&7))<<3) + k7] = bw0[j];
        }
        #pragma unroll
        for (int j = 0; j < 8; j++){
            int nn = ng*16 + 8 + j;
            Bs[nn*64 + ((kg^(nn&7))<<3) + k7] = bw1[j];
        }
        __syncthreads();
        if (c + 1 < NC){
            int k0 = (c+1)*64;
            a0p = *(const float4*)(Ab + baseA + (size_t)arow0*K + k0 + ag*8);
            a1p = *(const float4*)(Ab + baseA + (size_t)arow1*K + k0 + ag*8);
            b0p = *(const float4*)(Wb + (size_t)(k0+kr)*NH + cb*64 + ng*16);
            b1p = *(const float4*)(Wb + (size_t)(k0+kr)*NH + cb*64 + ng*16 + 8);
        }
        #pragma unroll
        for (int ks = 0; ks < 4; ks++){
            int gq = ks*2 + hi;
            v8s a = *(const v8s*)&As[ra0 + ((gq^fr7a)<<3)];
            v8s b = *(const v8s*)&Bs[rbp + ((gq^fr7b)<<3)];
            acc = __builtin_amdgcn_mfma_f32_32x32x16_bf16(a, b, acc, 0, 0, 0);
        }
    }
    int n  = cb*64 + wwc*32 + l31;
    int mb = rb*64 + wwr*32 + 4*hi;
    #pragma unroll
    for (int i = 0; i < 16; i++){
        int m = mb + (i&3) + 8*(i>>2);
        XW[(size_t)m*NH + n] = acc[i];
    }
}

// ---------------- fused pool + X@W + prev-layer readout (layers 2,3) -------
// A rows gathered on the fly: bf16(Xn[perm[r]]*svals[r]) — bit-identical to
// the old Pb path. cb==0 blocks also reduce the staged pooled tile into the
// previous layer's col-max/col-sum (bf16-rounded; within threshold).
__global__ __launch_bounds__(256) void k_xwp(const float* __restrict__ Xn,
        const int* __restrict__ perm, const float* __restrict__ svals,
        const ushort* __restrict__ Wb, float* __restrict__ XW, int M,
        uint* __restrict__ maxU, float* __restrict__ sums, int layer){
    int rb = blockIdx.x, cb = blockIdx.y;     // grid (M/64, 4); K = NH = 256
    __shared__ __align__(16) ushort As[64*64];
    __shared__ __align__(16) ushort Bs[64*64];
    __shared__ float pmx[256], psm[256];
    int tid = threadIdx.x, lane = tid & 63, wv = tid >> 6;
    int wwr = wv >> 1, wwc = wv & 1;
    int l31 = lane & 31, hi = lane >> 5;
    int arow0 = tid >> 3, ag = tid & 7;
    int arow1 = arow0 + 32;
    int da0 = arow0*64 + ((ag^(arow0&7))<<3);
    int da1 = arow1*64 + ((ag^(arow1&7))<<3);
    int p0 = perm[rb*64 + arow0]; float sv0 = svals[rb*64 + arow0];
    int p1 = perm[rb*64 + arow1]; float sv1 = svals[rb*64 + arow1];
    int kr = tid >> 2, ng = tid & 3;
    int kg = kr >> 3, k7 = kr & 7;
    int ra0 = (wwr*32 + l31)*64, rbp = (wwc*32 + l31)*64;
    int fr7a = (wwr*32 + l31) & 7, fr7b = (wwc*32 + l31) & 7;

    float4 xa0 = *(const float4*)(Xn + (size_t)p0*NH + ag*8);
    float4 xa1 = *(const float4*)(Xn + (size_t)p0*NH + ag*8 + 4);
    float4 xb0 = *(const float4*)(Xn + (size_t)p1*NH + ag*8);
    float4 xb1 = *(const float4*)(Xn + (size_t)p1*NH + ag*8 + 4);
    float4 wb0 = *(const float4*)(Wb + (size_t)kr*NH + cb*64 + ng*16);
    float4 wb1 = *(const float4*)(Wb + (size_t)kr*NH + cb*64 + ng*16 + 8);

    v16f acc = {};
    for (int c = 0; c < 4; c++){
        __syncthreads();
        {
            __align__(16) ushort ta[8];
            ta[0]=f2b(xa0.x*sv0); ta[1]=f2b(xa0.y*sv0); ta[2]=f2b(xa0.z*sv0); ta[3]=f2b(xa0.w*sv0);
            ta[4]=f2b(xa1.x*sv0); ta[5]=f2b(xa1.y*sv0); ta[6]=f2b(xa1.z*sv0); ta[7]=f2b(xa1.w*sv0);
            *(float4*)&As[da0] = *(const float4*)ta;
            __align__(16) ushort tb[8];
            tb[0]=f2b(xb0.x*sv1); tb[1]=f2b(xb0.y*sv1); tb[2]=f2b(xb0.z*sv1); tb[3]=f2b(xb0.w*sv1);
            tb[4]=f2b(xb1.x*sv1); tb[5]=f2b(xb1.y*sv1); tb[6]=f2b(xb1.z*sv1); tb[7]=f2b(xb1.w*sv1);
            *(float4*)&As[da1] = *(const float4*)tb;
        }
        {
            const ushort* bw0 = (const ushort*)&wb0;
            const ushort* bw1 = (const ushort*)&wb1;
            #pragma unroll
            for (int j = 0; j < 8; j++){
                int nn = ng*16 + j;
                Bs[nn*64 + ((kg^(nn&7))<<3) + k7] = bw0[j];
            }
            #pragma unroll
            for (int j = 0; j < 8; j++){
                int nn = ng*16 + 8 + j;
                Bs[nn*64 + ((kg^(nn&7))<<3) + k7] = bw1[j];
            }
        }
        __syncthreads();
        if (c < 3){
            int k0 = (c+1)*64;
            xa0 = *(const float4*)(Xn + (size_t)p0*NH + k0 + ag*8);
            xa1 = *(const float4*)(Xn + (size_t)p0*NH + k0 + ag*8 + 4);
            xb0 = *(const float4*)(Xn + (size_t)p1*NH + k0 + ag*8);
            xb1 = *(const float4*)(Xn + (size_t)p1*NH + k0 + ag*8 + 4);
            wb0 = *(const float4*)(Wb + (size_t)(k0+kr)*NH + cb*64 + ng*16);
            wb1 = *(const float4*)(Wb + (size_t)(k0+kr)*NH + cb*64 + ng*16 + 8);
        }
        if (cb == 0){
            int cc = tid & 63, q = tid >> 6;
            int gg = cc >> 3, c7 = cc & 7;
            float m = -INFINITY, s = 0.f;
            #pragma unroll
            for (int i = 0; i < 16; i++){
                int rr = q*16 + i;
                float v = __uint_as_float(((uint)As[rr*64 + ((gg^(rr&7))<<3) + c7]) << 16);
                m = fmaxf(m, v); s += v;
            }
            pmx[tid] = m; psm[tid] = s;
            __syncthreads();
            if (tid < 64){
                float mm = fmaxf(fmaxf(pmx[tid], pmx[tid+64]), fmaxf(pmx[tid+128], pmx[tid+192]));
                float ss = psm[tid] + psm[tid+64] + psm[tid+128] + psm[tid+192];
                atomicMax(&maxU[layer*NH + c*64 + tid], fcode(mm));
                atomicAdd(&sums[layer*NH + c*64 + tid], ss);
            }
        }
        #pragma unroll
        for (int ks = 0; ks < 4; ks++){
            int gq = ks*2 + hi;
            v8s a = *(const v8s*)&As[ra0 + ((gq^fr7a)<<3)];
            v8s b = *(const v8s*)&Bs[rbp + ((gq^fr7b)<<3)];
            acc = __builtin_amdgcn_mfma_f32_32x32x16_bf16(a, b, acc, 0, 0, 0);
        }
    }
    int n  = cb*64 + wwc*32 + l31;
    int mb = rb*64 + wwr*32 + 4*hi;
    #pragma unroll
    for (int i = 0; i < 16; i++){
        int m = mb + (i&3) + 8*(i>>2);
        XW[(size_t)m*NH + n] = acc[i];
    }
}

// ---- fused GCN finish: edge-scan aggregation + relu + scorer --------------
__global__ __launch_bounds__(256) void k_gcnscore(const float* __restrict__ XW,
        const unsigned* __restrict__ edges, const unsigned* __restrict__ ecnt, int slot,
        const float* __restrict__ deg, const void* __restrict__ b,
        const void* __restrict__ Wn, const void* __restrict__ Wr, const void* __restrict__ bs,
        const unsigned* __restrict__ fb, const unsigned* __restrict__ fWn,
        const unsigned* __restrict__ fWr, const unsigned* __restrict__ fbs,
        float* __restrict__ Xn, float* __restrict__ s1, float* __restrict__ z){
    int row = blockIdx.x, t = threadIdx.x;
    __shared__ unsigned eL[256];
    __shared__ unsigned Esh;
    if (t == 0){ unsigned E0 = ecnt[slot]; Esh = (E0 > EDGE_CAP) ? EDGE_CAP : E0; }
    __syncthreads();
    unsigned E = Esh;
    float disr = 1.0f / sqrtf(deg[row]);
    float acc = disr * XW[row*NH + t];
    for (unsigned base = 0; base < E; base += 256){
        unsigned nchunk = E - base; if (nchunk > 256) nchunk = 256;
        __syncthreads();
        if (t < nchunk) eL[t] = edges[base + t];
        __syncthreads();
        for (unsigned j = 0; j < nchunk; j++){
            unsigned ed = eL[j];
            if ((int)(ed >> 16) == row){
                int src = ed & 0xFFFFu;
                acc += (1.0f / sqrtf(deg[src])) * XW[src*NH + t];
            }
        }
    }
    float xn = fmaxf(fmaf(disr, acc, ldf(b, t, (int)fb[0])), 0.f);
    Xn[row*NH + t] = xn;
    float a  = xn * ldf(Wn, t, (int)fWn[0]);
    float bb = xn * ldf(Wr, t, (int)fWr[0]);
    for (int off = 32; off >= 1; off >>= 1){ a += __shfl_down(a, off); bb += __shfl_down(bb, off); }
    __shared__ float ra[4], rbv[4];
    int w = t >> 6;
    if ((t & 63) == 0){ ra[w] = a; rbv[w] = bb; }
    __syncthreads();
    if (t == 0){
        s1[row] = ra[0]+ra[1]+ra[2]+ra[3];
        z[row]  = rbv[0]+rbv[1]+rbv[2]+rbv[3] + ldf(bs, 0, (int)fbs[0]);
    }
}

// ---------------- fused: scoredge + bisection top-k select + efilter -------
__global__ __launch_bounds__(1024) void k_select(const float* __restrict__ z,
        const float* __restrict__ s1, int N, int k,
        const unsigned* __restrict__ eIn, unsigned* __restrict__ ecnt, int slotCur,
        unsigned* __restrict__ eOut, int slotOut,
        int* __restrict__ perm, float* __restrict__ svals,
        float* __restrict__ degN, int Nnext){
    __shared__ float zsh[4096];
    __shared__ int   rnk[4096];
    __shared__ uint  wcnt[16];
    __shared__ uint  wbase[16];
    __shared__ uint  sh[4];
    int t = threadIdx.x;
    int lane = t & 63, wv = t >> 6;
    for (int i = t; i < N; i += 1024){ zsh[i] = z[i]; rnk[i] = -1; }
    for (int i = t; i < Nnext; i += 1024) degN[i] = 1.0f;
    if (t == 0) sh[2] = 0u;
    __syncthreads();
    unsigned E = ecnt[slotCur]; if (E > EDGE_CAP) E = EDGE_CAP;
    for (unsigned e = t; e < E; e += 1024){
        unsigned ed = eIn[e];
        atomicAdd(&zsh[ed >> 16], s1[ed & 0xFFFFu]);
    }
    __syncthreads();
    bool v0 = t < N,        v1 = t+1024 < N,  v2 = t+2048 < N,  v3 = t+3072 < N;
    uint c0 = v0 ? fcode(zsh[t])      : 0u;
    uint c1 = v1 ? fcode(zsh[t+1024]) : 0u;
    uint c2 = v2 ? fcode(zsh[t+2048]) : 0u;
    uint c3 = v3 ? fcode(zsh[t+3072]) : 0u;
    uint T = 0u;
    for (int bit = 31; bit >= 0; bit--){
        uint cand = T | (1u << bit);
        uint c = (uint)__popcll(__ballot(v0 && c0 >= cand))
               + (uint)__popcll(__ballot(v1 && c1 >= cand))
               + (uint)__popcll(__ballot(v2 && c2 >= cand))
               + (uint)__popcll(__ballot(v3 && c3 >= cand));
        if (lane == 0) wcnt[wv] = c;
        __syncthreads();
        if (t == 0){ uint s = 0; for (int i = 0; i < 16; i++) s += wcnt[i]; sh[0] = s; }
        __syncthreads();
        if (sh[0] >= (uint)k) T = cand;
        __syncthreads();
    }
    ull b0 = __ballot(v0 && c0 > T), b1 = __ballot(v1 && c1 > T);
    ull b2 = __ballot(v2 && c2 > T), b3 = __ballot(v3 && c3 > T);
    uint t0 = (uint)__popcll(b0), t1 = (uint)__popcll(b1);
    uint t2 = (uint)__popcll(b2), t3 = (uint)__popcll(b3);
    if (lane == 0) wcnt[wv] = t0 + t1 + t2 + t3;
    __syncthreads();
    if (t == 0){
        uint s = 0;
        for (int i = 0; i < 16; i++){ wbase[i] = s; s += wcnt[i]; }
        sh[1] = s;
    }
    __syncthreads();
    uint cntGT = sh[1];
    uint rem = (uint)k - cntGT;
    ull ltm = ((ull)1 << lane) - 1;
    uint off = wbase[wv];
    if (v0 && c0 > T){ uint r = off + (uint)__popcll(b0 & ltm); int i = t;
        perm[r] = i; svals[r] = tanhf(zsh[i]); rnk[i] = (int)r; }
    off += t0;
    if (v1 && c1 > T){ uint r = off + (uint)__popcll(b1 & ltm); int i = t+1024;
        perm[r] = i; svals[r] = tanhf(zsh[i]); rnk[i] = (int)r; }
    off += t1;
    if (v2 && c2 > T){ uint r = off + (uint)__popcll(b2 & ltm); int i = t+2048;
        perm[r] = i; svals[r] = tanhf(zsh[i]); rnk[i] = (int)r; }
    off += t2;
    if (v3 && c3 > T){ uint r = off + (uint)__popcll(b3 & ltm); int i = t+3072;
        perm[r] = i; svals[r] = tanhf(zsh[i]); rnk[i] = (int)r; }
    #pragma unroll
    for (int j = 0; j < 4; j++){
        int i = t + j*1024;
        bool vv = (j==0) ? v0 : (j==1) ? v1 : (j==2) ? v2 : v3;
        uint cc = (j==0) ? c0 : (j==1) ? c1 : (j==2) ? c2 : c3;
        if (vv && cc == T){
            uint e = atomicAdd(&sh[2], 1u);
            if (e < rem){
                uint r = cntGT + e;
                perm[r] = i; svals[r] = tanhf(zsh[i]); rnk[i] = (int)r;
            }
        }
    }
    __syncthreads();
    if (slotOut >= 0){
        for (unsigned e = t; e < E; e += 1024){
            unsigned ed = eIn[e];
            int nd = rnk[ed >> 16], ns = rnk[ed & 0xFFFFu];
            if (nd >= 0 && ns >= 0){
                unsigned idx = atomicAdd(&ecnt[slotOut], 1u);
                if (idx < EDGE_CAP){
                    eOut[idx] = ((unsigned)nd << 16) | (unsigned)ns;
                    atomicAdd(&degN[nd], 1.0f);
                }
            }
        }
    }
}

// ---------------- layer-3 pool+readout (fp32-exact) + fused writeout -------
__global__ __launch_bounds__(256) void k_poolread3(const float* __restrict__ Xn,
        const int* __restrict__ perm, const float* __restrict__ svals, int k,
        uint* __restrict__ maxU, float* __restrict__ sums,
        unsigned* __restrict__ done, float* __restrict__ out){
    int b = blockIdx.x, t = threadIdx.x;
    float m = -INFINITY, s = 0.f;
    for (int r = b; r < k; r += 64){
        int p = perm[r];
        float v = Xn[p*NH + t] * svals[r];
        m = fmaxf(m, v); s += v;
    }
    atomicMax(&maxU[2*NH + t], fcode(m));
    atomicAdd(&sums[2*NH + t], s);
    __threadfence();
    __shared__ uint lastv;
    if (t == 0) lastv = atomicAdd(done, 1u);
    __syncthreads();
    if (lastv == 63u){
        // final combine; atomic loads for cross-XCD visibility
        uint m0 = atomicAdd(&maxU[t], 0u);
        uint m1 = atomicAdd(&maxU[NH + t], 0u);
        uint m2 = atomicAdd(&maxU[2*NH + t], 0u);
        float s0 = atomicAdd(&sums[t], 0.f);
        float s1v = atomicAdd(&sums[NH + t], 0.f);
        float s2 = atomicAdd(&sums[2*NH + t], 0.f);
        out[t] = fdecode(m0) + fdecode(m1) + fdecode(m2);
        out[NH + t] = s0*(1.0f/KL1) + s1v*(1.0f/KL2) + s2*(1.0f/KL3);
    }
}

// =======================================================================
extern "C" void kernel_launch(void* const* d_in, const int* in_sizes, int n_in,
                              void* d_out, int out_size, void* d_ws, size_t ws_size,
                              hipStream_t stream)
{
    const void* b1 = d_in[5];
    const void* b2 = d_in[7];
    const void* b3 = d_in[9];
    const void* Wr1 = d_in[10]; const void* Wn1 = d_in[11]; const void* bs1 = d_in[12];
    const void* Wr2 = d_in[13]; const void* Wn2 = d_in[14]; const void* bs2 = d_in[15];
    const void* Wr3 = d_in[16]; const void* Wn3 = d_in[17]; const void* bs3 = d_in[18];

    char* w = (char*)d_ws;
    auto alloc = [&](size_t bytes)->char*{ char* p = w; w += (bytes + 255) & ~(size_t)255; return p; };
    ushort*   Xb    = (ushort*)  alloc((size_t)NN*DIN*2);
    float*    Xn    = (float*)   alloc((size_t)NN*NH*4);
    float*    XW    = (float*)   alloc((size_t)NN*NH*4);
    ushort*   Wb    = (ushort*)  alloc((size_t)262144*2);
    unsigned* E0    = (unsigned*)alloc((size_t)EDGE_CAP*4);
    unsigned* E1    = (unsigned*)alloc((size_t)EDGE_CAP*4);
    float*    tmin  = (float*)   alloc(4096*4);
    float*    sq    = (float*)   alloc(NN*4);
    float*    degA  = (float*)   alloc(NN*4);
    float*    degB  = (float*)   alloc(NN*4);
    float*    s1    = (float*)   alloc(NN*4);
    float*    z     = (float*)   alloc(NN*4);
    int*      perm  = (int*)     alloc(NN*4);
    float*    svals = (float*)   alloc(NN*4);
    unsigned* ecnt  = (unsigned*)alloc(256);
    unsigned* maxd2 = (unsigned*)alloc(256);
    unsigned* dflag = (unsigned*)alloc(256);
    uint*     maxU  = (uint*)    alloc(768*4);
    float*    sums  = (float*)   alloc(768*4);
    (void)ws_size;

    DtIn da;
    for (int i = 0; i < 19; i++){ da.p[i] = d_in[i]; da.n[i] = in_sizes[i]; }

    k_prep<<<NN + 65, 512, 0, stream>>>(da, Xb, sq, Wb, dflag, degA, maxU, sums,
            ecnt, maxd2, tmin);
    dim3 gg(64, 64);
    k_gram<1><<<gg, 256, 0, stream>>>(Xb, sq, maxd2, tmin, ecnt, E0, degA);
    k_gram<2><<<gg, 256, 0, stream>>>(Xb, sq, maxd2, tmin, ecnt, E0, degA);

    // ---------------- layer 1 (N=4096 -> k=3072) ----------------
    k_xw<<<dim3(64,4), 256, 0, stream>>>(Xb, Wb, XW, NN, DIN);
    k_gcnscore<<<NN, 256, 0, stream>>>(XW, E0, ecnt, 0, degA, b1, Wn1, Wr1, bs1,
            dflag+5, dflag+11, dflag+10, dflag+12, Xn, s1, z);
    k_select<<<1, 1024, 0, stream>>>(z, s1, NN, KL1, E0, ecnt, 0, E1, 1,
            perm, svals, degB, KL1);

    // ---------------- layer 2 (N=3072 -> k=2304); fused pool1+readout ------
    k_xwp<<<dim3(48,4), 256, 0, stream>>>(Xn, perm, svals, Wb + 131072, XW, KL1,
            maxU, sums, 0);
    k_gcnscore<<<KL1, 256, 0, stream>>>(XW, E1, ecnt, 1, degB, b2, Wn2, Wr2, bs2,
            dflag+7, dflag+14, dflag+13, dflag+15, Xn, s1, z);
    k_select<<<1, 1024, 0, stream>>>(z, s1, KL1, KL2, E1, ecnt, 1, E0, 2,
            perm, svals, degA, KL2);

    // ---------------- layer 3 (N=2304 -> k=1728); fused pool2+readout ------
    k_xwp<<<dim3(36,4), 256, 0, stream>>>(Xn, perm, svals, Wb + 196608, XW, KL2,
            maxU, sums, 1);
    k_gcnscore<<<KL2, 256, 0, stream>>>(XW, E0, ecnt, 2, degA, b3, Wn3, Wr3, bs3,
            dflag+9, dflag+17, dflag+16, dflag+18, Xn, s1, z);
    k_select<<<1, 1024, 0, stream>>>(z, s1, KL2, KL3, E0, ecnt, 2,
            (unsigned*)nullptr, -1, perm, svals, degB, 0);
    k_poolread3<<<64, 256, 0, stream>>>(Xn, perm, svals, KL3, maxU, sums,
            ecnt + 3, (float*)d_out);
}